// Round 10
// baseline (98.907 us; speedup 1.0000x reference)
//
#include <hip/hip_runtime.h>

#define DD 64
#define LL 200
#define LP 256     // LL padded
#define GG 6
#define LAMBDA 0.001f
#define FP8_BLOCKS 3126   // ceil(100001*64/8 / 256)

typedef __attribute__((ext_vector_type(8))) short s8v;   // 8 bf16 (4 VGPRs)
typedef __attribute__((ext_vector_type(4))) float f4v;   // MFMA accumulator
typedef __attribute__((ext_vector_type(2))) float f2v;

__device__ __forceinline__ float wave_reduce_sum(float v) {
    #pragma unroll
    for (int off = 32; off > 0; off >>= 1)
        v += __shfl_xor(v, off, 64);
    return v;
}

__device__ __forceinline__ unsigned short f2bf(float f) {
    union { float f; unsigned int u; } v; v.f = f;
    return (unsigned short)((v.u + 0x7FFFu + ((v.u >> 16) & 1u)) >> 16);  // RNE
}

//======================================================================
// Kernel 0: fused prep.
//  blocks [0, FP8_BLOCKS): emb_item fp32 -> fp8 e4m3 (x64 scale) table
//  blocks [FP8_BLOCKS, +36): 4 MLP weight matrices -> frag-order bf16 blob
//======================================================================
__global__ __launch_bounds__(256)
void prep_kernel(const float* __restrict__ emb_item,
                 const float* __restrict__ ut_w1, const float* __restrict__ ut_w2,
                 const float* __restrict__ it_w1, const float* __restrict__ it_w2,
                 unsigned int* __restrict__ emb8,          // [V*16] uints (4 fp8 each)
                 unsigned short* __restrict__ blob, int n8)
{
    if (blockIdx.x < FP8_BLOCKS) {
        const int i = blockIdx.x * 256 + threadIdx.x;
        if (i < n8) {
            const float4 f0 = *(const float4*)&emb_item[(size_t)i * 8];
            const float4 f1 = *(const float4*)&emb_item[(size_t)i * 8 + 4];
            int lo = __builtin_amdgcn_cvt_pk_fp8_f32(f0.x * 64.f, f0.y * 64.f, 0, false);
            lo     = __builtin_amdgcn_cvt_pk_fp8_f32(f0.z * 64.f, f0.w * 64.f, lo, true);
            int hi = __builtin_amdgcn_cvt_pk_fp8_f32(f1.x * 64.f, f1.y * 64.f, 0, false);
            hi     = __builtin_amdgcn_cvt_pk_fp8_f32(f1.z * 64.f, f1.w * 64.f, hi, true);
            uint2 o; o.x = (unsigned int)lo; o.y = (unsigned int)hi;
            *(uint2*)&emb8[(size_t)i * 2] = o;
        }
        return;
    }
    const int s = (blockIdx.x - FP8_BLOCKS) * 256 + threadIdx.x;   // 0..9215
    if (s >= 9216) return;
    const float* src; int K, NT, r, k8; size_t obase;
    if (s < 4096)      { src = ut_w1; K = 256; NT = 8; r = s >> 5;          k8 = s & 31;          obase = 0; }
    else if (s < 5120) { src = ut_w2; K = 128; NT = 4; r = (s-4096) >> 4;   k8 = (s-4096) & 15;   obase = 4096; }
    else if (s < 8192) { src = it_w1; K = 192; NT = 8; r = (s-5120) / 24;   k8 = (s-5120) % 24;   obase = 5120; }
    else               { src = it_w2; K = 128; NT = 4; r = (s-8192) >> 4;   k8 = (s-8192) & 15;   obase = 8192; }
    const int k = k8 * 8;
    const float4 f0 = *(const float4*)&src[(size_t)r * K + k];
    const float4 f1 = *(const float4*)&src[(size_t)r * K + k + 4];
    const int ks = k >> 5, lg = (k >> 3) & 3;
    const int lp = lg * 16 + (r & 15), nt = r >> 4;
    const size_t slot = obase + (size_t)(ks * NT + nt) * 64 + lp;
    s8v wv;
    wv[0]=(short)f2bf(f0.x); wv[1]=(short)f2bf(f0.y); wv[2]=(short)f2bf(f0.z); wv[3]=(short)f2bf(f0.w);
    wv[4]=(short)f2bf(f1.x); wv[5]=(short)f2bf(f1.y); wv[6]=(short)f2bf(f1.z); wv[7]=(short)f2bf(f1.w);
    *(s8v*)&blob[slot * 8] = wv;
}

//======================================================================
// X/H fragment slot: A-operand layout for mfma_f32_16x16x32_bf16:
//   lane' = ((d>>3)&3)*16 + (r&15),  j = d&7,  k-step = d>>5
//======================================================================
#define PUT_FRAG(buf, NKS, r, d, val)                                   \
    do {                                                                \
        const int _mt = (r) >> 4, _ks = (d) >> 5;                       \
        const int _lp = (((d) >> 3) & 3) * 16 + ((r) & 15);             \
        (buf)[(((_mt) * (NKS) + _ks) * 64 + _lp) * 8 + ((d) & 7)] = f2bf(val); \
    } while (0)

//======================================================================
// Kernel 1: mega towers. blocks [0,nU): user (incl. inline hist pooling);
// [nU,2nU): item. Weights read directly from frag-ordered global blob.
//======================================================================
__global__ __launch_bounds__(512, 4)
void towers_kernel(
    const int* __restrict__ user_id, const int* __restrict__ top_genres,
    const int* __restrict__ item_id, const int* __restrict__ tmdb_genres,
    const int* __restrict__ history, const float* __restrict__ ts_diff,
    const uint2* __restrict__ emb8,
    const float* __restrict__ u_avg, const float* __restrict__ activity,
    const float* __restrict__ rel_year, const float* __restrict__ i_avg,
    const float* __restrict__ revenue,
    const float* __restrict__ emb_item, const float* __restrict__ emb_genre,
    const float* __restrict__ emb_user,
    const float* __restrict__ ut_cont_w, const float* __restrict__ ut_cont_b,
    const float* __restrict__ it_cont_w, const float* __restrict__ it_cont_b,
    const unsigned short* __restrict__ wblob,
    const float* __restrict__ ut_b1, const float* __restrict__ ut_g,
    const float* __restrict__ ut_be, const float* __restrict__ ut_b2,
    const float* __restrict__ it_b1, const float* __restrict__ it_g,
    const float* __restrict__ it_be, const float* __restrict__ it_b2,
    float* __restrict__ out, int B)
{
    const int tid = threadIdx.x, wave = tid >> 6, lane = tid & 63;
    const int nU = B / 64;
    const bool is_user = (int)blockIdx.x < nU;
    const int r0 = (is_user ? blockIdx.x : blockIdx.x - nU) * 64;

    __shared__ __align__(16) unsigned char  sC[64 * 128 * 4];     // 32KB: Xfrag -> y -> o
    __shared__ __align__(16) unsigned short sHf[4 * 4 * 64 * 8];  // 16KB
    __shared__ __align__(16) float2 s_p[8][LP];                   // 16KB (user hist)

    unsigned short* sXf = (unsigned short*)sC;
    float* sY = (float*)sC;
    float* sO = (float*)sC;

    const int mh = wave >> 2, nh = wave & 3;
    const f4v zero4 = {0.f, 0.f, 0.f, 0.f};

    if (is_user) {
        const int grp = lane >> 3;    // entry subgroup 0..7
        const int c8 = lane & 7;      // 8-dim chunk within row

        //---- phase A: features + inline hist pooling (wave-private rows) ----
        for (int i = 0; i < 8; ++i) {
            const int r = wave * 8 + i, b = r0 + r;
            // standard features (lane = dim)
            const float ue = emb_user[(size_t)user_id[b] * DD + lane];
            const int* grow = top_genres + (size_t)b * GG;
            float gacc = 0.f, gw = 0.f;
            #pragma unroll
            for (int g = 0; g < GG; ++g) {
                const int idx = grow[g];
                const float m = (idx > 0) ? 1.f : 0.f;
                gacc = fmaf(m, emb_genre[idx * DD + lane], gacc);
                gw += m;
            }
            const float ug = gacc / (gw + 1e-8f);
            float uc = fmaf(u_avg[b], ut_cont_w[lane * 2 + 0],
                       fmaf(activity[b], ut_cont_w[lane * 2 + 1], ut_cont_b[lane]));
            uc = fmaxf(uc, 0.f);
            PUT_FRAG(sXf, 8, r, lane, ue);
            PUT_FRAG(sXf, 8, r, 128 + lane, ug);
            PUT_FRAG(sXf, 8, r, 192 + lane, uc);

            // hist pooling for row b (wave-private s_p, no barrier needed)
            const int*   hrow = history + (size_t)b * LL;
            const float* trow = ts_diff + (size_t)b * LL;
            float wpart = 0.f;
            #pragma unroll
            for (int l = lane; l < LP; l += 64) {
                int idx = 0; float w = 0.f;
                if (l < LL) {
                    const int raw = hrow[l];
                    if (raw > 0) { w = __expf(-LAMBDA * trow[l]); idx = raw; }
                }
                s_p[wave][l] = make_float2(w, __int_as_float(idx));
                wpart += w;
            }
            const float wsum = wave_reduce_sum(wpart);

            float a[8];
            #pragma unroll
            for (int j = 0; j < 8; ++j) a[j] = 0.f;
            #pragma unroll 1
            for (int l0 = 0; l0 < LP; l0 += 128) {
                uint2 e[16]; float w[16];
                #pragma unroll
                for (int k = 0; k < 16; ++k) {
                    const float2 p = s_p[wave][l0 + k * 8 + grp];
                    w[k] = p.x;
                    e[k] = emb8[(size_t)__float_as_int(p.y) * 8 + c8];
                }
                #pragma unroll
                for (int k = 0; k < 16; ++k) {
                    const f2v d01 = __builtin_amdgcn_cvt_pk_f32_fp8((int)e[k].x, false);
                    const f2v d23 = __builtin_amdgcn_cvt_pk_f32_fp8((int)e[k].x, true);
                    const f2v d45 = __builtin_amdgcn_cvt_pk_f32_fp8((int)e[k].y, false);
                    const f2v d67 = __builtin_amdgcn_cvt_pk_f32_fp8((int)e[k].y, true);
                    a[0] = fmaf(w[k], d01[0], a[0]);
                    a[1] = fmaf(w[k], d01[1], a[1]);
                    a[2] = fmaf(w[k], d23[0], a[2]);
                    a[3] = fmaf(w[k], d23[1], a[3]);
                    a[4] = fmaf(w[k], d45[0], a[4]);
                    a[5] = fmaf(w[k], d45[1], a[5]);
                    a[6] = fmaf(w[k], d67[0], a[6]);
                    a[7] = fmaf(w[k], d67[1], a[7]);
                }
            }
            #pragma unroll
            for (int off = 8; off <= 32; off <<= 1)
                #pragma unroll
                for (int j = 0; j < 8; ++j)
                    a[j] += __shfl_xor(a[j], off, 64);

            if (grp == 0) {
                const float inv = 0.015625f / (wsum + 1e-8f);  // 1/64 descale
                #pragma unroll
                for (int j = 0; j < 8; ++j)
                    PUT_FRAG(sXf, 8, r, 64 + c8 * 8 + j, a[j] * inv);
            }
        }
        __syncthreads();

        //---- L1 MFMA: M=64, N=128, K=256; B-operand from global blob ----
        f4v acc[2][2];
        #pragma unroll
        for (int a2 = 0; a2 < 2; ++a2)
            #pragma unroll
            for (int c = 0; c < 2; ++c) acc[a2][c] = zero4;
        #pragma unroll
        for (int ks = 0; ks < 8; ++ks) {
            s8v av[2], bv[2];
            #pragma unroll
            for (int ml = 0; ml < 2; ++ml)
                av[ml] = *(const s8v*)&sXf[(((mh * 2 + ml) * 8 + ks) * 64 + lane) * 8];
            #pragma unroll
            for (int nl = 0; nl < 2; ++nl)
                bv[nl] = *(const s8v*)&wblob[((ks * 8 + nh * 2 + nl) * 64 + lane) * 8];
            #pragma unroll
            for (int ml = 0; ml < 2; ++ml)
                #pragma unroll
                for (int nl = 0; nl < 2; ++nl)
                    acc[ml][nl] = __builtin_amdgcn_mfma_f32_16x16x32_bf16(av[ml], bv[nl], acc[ml][nl], 0, 0, 0);
        }
        __syncthreads();

        #pragma unroll
        for (int ml = 0; ml < 2; ++ml) {
            #pragma unroll
            for (int nl = 0; nl < 2; ++nl) {
                const int n = (nh * 2 + nl) * 16 + (lane & 15);
                const float bb = ut_b1[n];
                #pragma unroll
                for (int rg = 0; rg < 4; ++rg) {
                    const int m = (mh * 2 + ml) * 16 + (lane >> 4) * 4 + rg;
                    sY[m * 128 + n] = acc[ml][nl][rg] + bb;
                }
            }
        }
        __syncthreads();

        {
            const float g0 = ut_g[lane], g1 = ut_g[lane + 64];
            const float e0 = ut_be[lane], e1 = ut_be[lane + 64];
            for (int i = 0; i < 8; ++i) {
                const int r = wave * 8 + i;
                const float a = sY[r * 128 + lane];
                const float c = sY[r * 128 + 64 + lane];
                const float mean = wave_reduce_sum(a + c) * (1.f / 128.f);
                const float da = a - mean, dc = c - mean;
                const float var = wave_reduce_sum(da * da + dc * dc) * (1.f / 128.f);
                const float rstd = rsqrtf(var + 1e-5f);
                const float h0 = fmaxf(fmaf(da * rstd, g0, e0), 0.f);
                const float h1 = fmaxf(fmaf(dc * rstd, g1, e1), 0.f);
                PUT_FRAG(sHf, 4, r, lane, h0);
                PUT_FRAG(sHf, 4, r, 64 + lane, h1);
            }
        }
        __syncthreads();

        f4v acc2[2];
        acc2[0] = zero4; acc2[1] = zero4;
        #pragma unroll
        for (int ks = 0; ks < 4; ++ks) {
            s8v av[2], bv;
            #pragma unroll
            for (int ml = 0; ml < 2; ++ml)
                av[ml] = *(const s8v*)&sHf[(((mh * 2 + ml) * 4 + ks) * 64 + lane) * 8];
            bv = *(const s8v*)&wblob[(4096 + (ks * 4 + nh) * 64 + lane) * 8];
            #pragma unroll
            for (int ml = 0; ml < 2; ++ml)
                acc2[ml] = __builtin_amdgcn_mfma_f32_16x16x32_bf16(av[ml], bv, acc2[ml], 0, 0, 0);
        }
        #pragma unroll
        for (int ml = 0; ml < 2; ++ml) {
            const int n = nh * 16 + (lane & 15);
            const float bb = ut_b2[n];
            #pragma unroll
            for (int rg = 0; rg < 4; ++rg) {
                const int m = (mh * 2 + ml) * 16 + (lane >> 4) * 4 + rg;
                sO[m * 64 + n] = acc2[ml][rg] + bb;
            }
        }
        __syncthreads();

        for (int i = 0; i < 8; ++i) {
            const int r = wave * 8 + i;
            const float o = sO[r * 64 + lane];
            const float nrm = sqrtf(wave_reduce_sum(o * o));
            out[(size_t)(r0 + r) * DD + lane] = o / fmaxf(nrm, 1e-12f);
        }
    } else {
        //================= item tower =================
        #pragma unroll 2
        for (int i = 0; i < 8; ++i) {
            const int r = wave * 8 + i, b = r0 + r;
            const float ie = emb_item[(size_t)item_id[b] * DD + lane];
            const int* grow = tmdb_genres + (size_t)b * GG;
            float gacc = 0.f, gw = 0.f;
            #pragma unroll
            for (int g = 0; g < GG; ++g) {
                const int idx = grow[g];
                const float m = (idx > 0) ? 1.f : 0.f;
                gacc = fmaf(m, emb_genre[idx * DD + lane], gacc);
                gw += m;
            }
            const float ig = gacc / (gw + 1e-8f);
            float ic = fmaf(rel_year[b], it_cont_w[lane * 3 + 0],
                       fmaf(i_avg[b],   it_cont_w[lane * 3 + 1],
                       fmaf(revenue[b], it_cont_w[lane * 3 + 2], it_cont_b[lane])));
            ic = fmaxf(ic, 0.f);
            PUT_FRAG(sXf, 6, r, lane, ie);
            PUT_FRAG(sXf, 6, r, 64 + lane, ig);
            PUT_FRAG(sXf, 6, r, 128 + lane, ic);
        }
        __syncthreads();

        f4v acc[2][2];
        #pragma unroll
        for (int a2 = 0; a2 < 2; ++a2)
            #pragma unroll
            for (int c = 0; c < 2; ++c) acc[a2][c] = zero4;
        #pragma unroll
        for (int ks = 0; ks < 6; ++ks) {
            s8v av[2], bv[2];
            #pragma unroll
            for (int ml = 0; ml < 2; ++ml)
                av[ml] = *(const s8v*)&sXf[(((mh * 2 + ml) * 6 + ks) * 64 + lane) * 8];
            #pragma unroll
            for (int nl = 0; nl < 2; ++nl)
                bv[nl] = *(const s8v*)&wblob[(5120 + (ks * 8 + nh * 2 + nl) * 64 + lane) * 8];
            #pragma unroll
            for (int ml = 0; ml < 2; ++ml)
                #pragma unroll
                for (int nl = 0; nl < 2; ++nl)
                    acc[ml][nl] = __builtin_amdgcn_mfma_f32_16x16x32_bf16(av[ml], bv[nl], acc[ml][nl], 0, 0, 0);
        }
        __syncthreads();

        #pragma unroll
        for (int ml = 0; ml < 2; ++ml) {
            #pragma unroll
            for (int nl = 0; nl < 2; ++nl) {
                const int n = (nh * 2 + nl) * 16 + (lane & 15);
                const float bb = it_b1[n];
                #pragma unroll
                for (int rg = 0; rg < 4; ++rg) {
                    const int m = (mh * 2 + ml) * 16 + (lane >> 4) * 4 + rg;
                    sY[m * 128 + n] = acc[ml][nl][rg] + bb;
                }
            }
        }
        __syncthreads();

        {
            const float g0 = it_g[lane], g1 = it_g[lane + 64];
            const float e0 = it_be[lane], e1 = it_be[lane + 64];
            for (int i = 0; i < 8; ++i) {
                const int r = wave * 8 + i;
                const float a = sY[r * 128 + lane];
                const float c = sY[r * 128 + 64 + lane];
                const float mean = wave_reduce_sum(a + c) * (1.f / 128.f);
                const float da = a - mean, dc = c - mean;
                const float var = wave_reduce_sum(da * da + dc * dc) * (1.f / 128.f);
                const float rstd = rsqrtf(var + 1e-5f);
                const float h0 = fmaxf(fmaf(da * rstd, g0, e0), 0.f);
                const float h1 = fmaxf(fmaf(dc * rstd, g1, e1), 0.f);
                PUT_FRAG(sHf, 4, r, lane, h0);
                PUT_FRAG(sHf, 4, r, 64 + lane, h1);
            }
        }
        __syncthreads();

        f4v acc2[2];
        acc2[0] = zero4; acc2[1] = zero4;
        #pragma unroll
        for (int ks = 0; ks < 4; ++ks) {
            s8v av[2], bv;
            #pragma unroll
            for (int ml = 0; ml < 2; ++ml)
                av[ml] = *(const s8v*)&sHf[(((mh * 2 + ml) * 4 + ks) * 64 + lane) * 8];
            bv = *(const s8v*)&wblob[(8192 + (ks * 4 + nh) * 64 + lane) * 8];
            #pragma unroll
            for (int ml = 0; ml < 2; ++ml)
                acc2[ml] = __builtin_amdgcn_mfma_f32_16x16x32_bf16(av[ml], bv, acc2[ml], 0, 0, 0);
        }
        #pragma unroll
        for (int ml = 0; ml < 2; ++ml) {
            const int n = nh * 16 + (lane & 15);
            const float bb = it_b2[n];
            #pragma unroll
            for (int rg = 0; rg < 4; ++rg) {
                const int m = (mh * 2 + ml) * 16 + (lane >> 4) * 4 + rg;
                sO[m * 64 + n] = acc2[ml][rg] + bb;
            }
        }
        __syncthreads();

        for (int i = 0; i < 8; ++i) {
            const int r = wave * 8 + i;
            const float o = sO[r * 64 + lane];
            const float nrm = sqrtf(wave_reduce_sum(o * o));
            out[(size_t)B * DD + (size_t)(r0 + r) * DD + lane] = o / fmaxf(nrm, 1e-12f);
        }
    }
}

extern "C" void kernel_launch(void* const* d_in, const int* in_sizes, int n_in,
                              void* d_out, int out_size, void* d_ws, size_t ws_size,
                              hipStream_t stream) {
    const int*   user_id     = (const int*)  d_in[0];
    const int*   history     = (const int*)  d_in[1];
    const int*   top_genres  = (const int*)  d_in[2];
    const int*   item_id     = (const int*)  d_in[3];
    const int*   tmdb_genres = (const int*)  d_in[4];
    const float* ts_diff     = (const float*)d_in[5];
    const float* u_avg       = (const float*)d_in[6];
    const float* activity    = (const float*)d_in[7];
    const float* rel_year    = (const float*)d_in[8];
    const float* i_avg       = (const float*)d_in[9];
    const float* revenue     = (const float*)d_in[10];
    const float* emb_item    = (const float*)d_in[11];
    const float* emb_genre   = (const float*)d_in[12];
    const float* emb_user    = (const float*)d_in[13];
    const float* ut_cont_w   = (const float*)d_in[14];
    const float* ut_cont_b   = (const float*)d_in[15];
    const float* ut_w1       = (const float*)d_in[16];
    const float* ut_b1       = (const float*)d_in[17];
    const float* ut_g        = (const float*)d_in[18];
    const float* ut_be       = (const float*)d_in[19];
    const float* ut_w2       = (const float*)d_in[20];
    const float* ut_b2       = (const float*)d_in[21];
    const float* it_cont_w   = (const float*)d_in[22];
    const float* it_cont_b   = (const float*)d_in[23];
    const float* it_w1       = (const float*)d_in[24];
    const float* it_b1       = (const float*)d_in[25];
    const float* it_g        = (const float*)d_in[26];
    const float* it_be       = (const float*)d_in[27];
    const float* it_w2       = (const float*)d_in[28];
    const float* it_b2       = (const float*)d_in[29];

    const int B = in_sizes[0];                 // 16384
    const int n_item = in_sizes[11];           // V_ITEM * 64

    // workspace layout
    unsigned int* emb8 = (unsigned int*)d_ws;                         // 6.4MB
    size_t off = (size_t)(n_item / 4) * sizeof(unsigned int);
    off = (off + 255) & ~(size_t)255;
    unsigned short* wblob = (unsigned short*)((char*)d_ws + off);     // 144KB

    hipLaunchKernelGGL(prep_kernel, dim3(FP8_BLOCKS + 36), dim3(256), 0, stream,
        emb_item, ut_w1, ut_w2, it_w1, it_w2, emb8, wblob, n_item / 8);

    hipLaunchKernelGGL(towers_kernel, dim3(2 * (B / 64)), dim3(512), 0, stream,
        user_id, top_genres, item_id, tmdb_genres, history, ts_diff,
        (const uint2*)emb8,
        u_avg, activity, rel_year, i_avg, revenue,
        emb_item, emb_genre, emb_user,
        ut_cont_w, ut_cont_b, it_cont_w, it_cont_b,
        wblob, ut_b1, ut_g, ut_be, ut_b2, it_b1, it_g, it_be, it_b2,
        (float*)d_out, B);
}

// Round 11
// 76.100 us; speedup vs baseline: 1.2997x; 1.2997x over previous
//
#include <hip/hip_runtime.h>

#define DD 64
#define LL 200
#define LP 256     // LL padded
#define GG 6
#define LAMBDA 0.001f
#define FP8_BLOCKS 3126   // ceil(100001*64/8 / 256)

typedef __attribute__((ext_vector_type(8))) short s8v;   // 8 bf16 (4 VGPRs)
typedef __attribute__((ext_vector_type(4))) float f4v;   // MFMA accumulator
typedef __attribute__((ext_vector_type(2))) float f2v;

__device__ __forceinline__ float wave_reduce_sum(float v) {
    #pragma unroll
    for (int off = 32; off > 0; off >>= 1)
        v += __shfl_xor(v, off, 64);
    return v;
}

__device__ __forceinline__ unsigned short f2bf(float f) {
    union { float f; unsigned int u; } v; v.f = f;
    return (unsigned short)((v.u + 0x7FFFu + ((v.u >> 16) & 1u)) >> 16);  // RNE
}

//======================================================================
// Kernel 0: fused prep.
//  blocks [0, FP8_BLOCKS): emb_item fp32 -> fp8 e4m3 (x64 scale) table
//  blocks [FP8_BLOCKS, +36): 4 MLP weight matrices -> frag-order bf16 blob
//======================================================================
__global__ __launch_bounds__(256)
void prep_kernel(const float* __restrict__ emb_item,
                 const float* __restrict__ ut_w1, const float* __restrict__ ut_w2,
                 const float* __restrict__ it_w1, const float* __restrict__ it_w2,
                 unsigned int* __restrict__ emb8,          // [V*16] uints (4 fp8 each)
                 unsigned short* __restrict__ blob, int n8)
{
    if (blockIdx.x < FP8_BLOCKS) {
        const int i = blockIdx.x * 256 + threadIdx.x;
        if (i < n8) {
            const float4 f0 = *(const float4*)&emb_item[(size_t)i * 8];
            const float4 f1 = *(const float4*)&emb_item[(size_t)i * 8 + 4];
            int lo = __builtin_amdgcn_cvt_pk_fp8_f32(f0.x * 64.f, f0.y * 64.f, 0, false);
            lo     = __builtin_amdgcn_cvt_pk_fp8_f32(f0.z * 64.f, f0.w * 64.f, lo, true);
            int hi = __builtin_amdgcn_cvt_pk_fp8_f32(f1.x * 64.f, f1.y * 64.f, 0, false);
            hi     = __builtin_amdgcn_cvt_pk_fp8_f32(f1.z * 64.f, f1.w * 64.f, hi, true);
            uint2 o; o.x = (unsigned int)lo; o.y = (unsigned int)hi;
            *(uint2*)&emb8[(size_t)i * 2] = o;
        }
        return;
    }
    const int s = (blockIdx.x - FP8_BLOCKS) * 256 + threadIdx.x;   // 0..9215
    if (s >= 9216) return;
    const float* src; int K, NT, r, k8; size_t obase;
    if (s < 4096)      { src = ut_w1; K = 256; NT = 8; r = s >> 5;          k8 = s & 31;          obase = 0; }
    else if (s < 5120) { src = ut_w2; K = 128; NT = 4; r = (s-4096) >> 4;   k8 = (s-4096) & 15;   obase = 4096; }
    else if (s < 8192) { src = it_w1; K = 192; NT = 8; r = (s-5120) / 24;   k8 = (s-5120) % 24;   obase = 5120; }
    else               { src = it_w2; K = 128; NT = 4; r = (s-8192) >> 4;   k8 = (s-8192) & 15;   obase = 8192; }
    const int k = k8 * 8;
    const float4 f0 = *(const float4*)&src[(size_t)r * K + k];
    const float4 f1 = *(const float4*)&src[(size_t)r * K + k + 4];
    const int ks = k >> 5, lg = (k >> 3) & 3;
    const int lp = lg * 16 + (r & 15), nt = r >> 4;
    const size_t slot = obase + (size_t)(ks * NT + nt) * 64 + lp;
    s8v wv;
    wv[0]=(short)f2bf(f0.x); wv[1]=(short)f2bf(f0.y); wv[2]=(short)f2bf(f0.z); wv[3]=(short)f2bf(f0.w);
    wv[4]=(short)f2bf(f1.x); wv[5]=(short)f2bf(f1.y); wv[6]=(short)f2bf(f1.z); wv[7]=(short)f2bf(f1.w);
    *(s8v*)&blob[slot * 8] = wv;
}

//======================================================================
// X/H fragment slot: A-operand layout for mfma_f32_16x16x32_bf16:
//   lane' = ((d>>3)&3)*16 + (r&15),  j = d&7,  k-step = d>>5
//======================================================================
#define PUT_FRAG(buf, NKS, r, d, val)                                   \
    do {                                                                \
        const int _mt = (r) >> 4, _ks = (d) >> 5;                       \
        const int _lp = (((d) >> 3) & 3) * 16 + ((r) & 15);             \
        (buf)[(((_mt) * (NKS) + _ks) * 64 + _lp) * 8 + ((d) & 7)] = f2bf(val); \
    } while (0)

//======================================================================
// Kernel 1: item tower (blocks [0,nI)) + history pooling (blocks [nI,..)).
// Item work overlaps the byte-bound fp8 gather on neighboring CUs.
//======================================================================
__global__ __launch_bounds__(512, 4)
void hist_item_kernel(
    const int* __restrict__ item_id, const int* __restrict__ tmdb_genres,
    const int* __restrict__ history, const float* __restrict__ ts_diff,
    const uint2* __restrict__ emb8,
    const float* __restrict__ rel_year, const float* __restrict__ i_avg,
    const float* __restrict__ revenue,
    const float* __restrict__ emb_item, const float* __restrict__ emb_genre,
    const float* __restrict__ it_cont_w, const float* __restrict__ it_cont_b,
    const unsigned short* __restrict__ wblob,
    const float* __restrict__ it_b1, const float* __restrict__ it_g,
    const float* __restrict__ it_be, const float* __restrict__ it_b2,
    float* __restrict__ hist_pool, float* __restrict__ out, int B)
{
    const int tid = threadIdx.x, wave = tid >> 6, lane = tid & 63;
    const int nI = B / 64;

    __shared__ __align__(16) unsigned char smem[48 * 1024];

    if ((int)blockIdx.x >= nI) {
        //================= history pooling: 8 waves x 1 row =================
        const int b = ((int)blockIdx.x - nI) * 8 + wave;
        const int grp = lane >> 3;    // entry subgroup 0..7
        const int c8 = lane & 7;      // 8-dim chunk within row
        float2* sp = (float2*)smem + wave * LP;   // wave-private 2KB slice

        const int*   hrow = history + (size_t)b * LL;
        const float* trow = ts_diff + (size_t)b * LL;

        float wpart = 0.f;
        #pragma unroll
        for (int l = lane; l < LP; l += 64) {
            int idx = 0; float w = 0.f;
            if (l < LL) {
                const int raw = hrow[l];
                if (raw > 0) { w = __expf(-LAMBDA * trow[l]); idx = raw; }
            }
            sp[l] = make_float2(w, __int_as_float(idx));
            wpart += w;
        }
        const float wsum = wave_reduce_sum(wpart);

        float a[8];
        #pragma unroll
        for (int j = 0; j < 8; ++j) a[j] = 0.f;

        #pragma unroll 1
        for (int l0 = 0; l0 < LP; l0 += 128) {
            uint2 e[16]; float w[16];
            #pragma unroll
            for (int i = 0; i < 16; ++i) {
                const float2 p = sp[l0 + i * 8 + grp];
                w[i] = p.x;
                e[i] = emb8[(size_t)__float_as_int(p.y) * 8 + c8];
            }
            #pragma unroll
            for (int i = 0; i < 16; ++i) {
                const f2v d01 = __builtin_amdgcn_cvt_pk_f32_fp8((int)e[i].x, false);
                const f2v d23 = __builtin_amdgcn_cvt_pk_f32_fp8((int)e[i].x, true);
                const f2v d45 = __builtin_amdgcn_cvt_pk_f32_fp8((int)e[i].y, false);
                const f2v d67 = __builtin_amdgcn_cvt_pk_f32_fp8((int)e[i].y, true);
                a[0] = fmaf(w[i], d01[0], a[0]);
                a[1] = fmaf(w[i], d01[1], a[1]);
                a[2] = fmaf(w[i], d23[0], a[2]);
                a[3] = fmaf(w[i], d23[1], a[3]);
                a[4] = fmaf(w[i], d45[0], a[4]);
                a[5] = fmaf(w[i], d45[1], a[5]);
                a[6] = fmaf(w[i], d67[0], a[6]);
                a[7] = fmaf(w[i], d67[1], a[7]);
            }
        }
        #pragma unroll
        for (int off = 8; off <= 32; off <<= 1)
            #pragma unroll
            for (int j = 0; j < 8; ++j)
                a[j] += __shfl_xor(a[j], off, 64);

        if (grp == 0) {
            const float inv = 0.015625f / (wsum + 1e-8f);   // 1/64 descale folded in
            float4 o0 = make_float4(a[0]*inv, a[1]*inv, a[2]*inv, a[3]*inv);
            float4 o1 = make_float4(a[4]*inv, a[5]*inv, a[6]*inv, a[7]*inv);
            *(float4*)&hist_pool[(size_t)b * DD + c8 * 8]     = o0;
            *(float4*)&hist_pool[(size_t)b * DD + c8 * 8 + 4] = o1;
        }
        return;
    }

    //================= item tower =================
    const int r0 = blockIdx.x * 64;
    unsigned short* sXf = (unsigned short*)smem;
    float* sY = (float*)smem;
    float* sO = (float*)smem;
    unsigned short* sHf = (unsigned short*)(smem + 32 * 1024);

    const int mh = wave >> 2, nh = wave & 3;
    const f4v zero4 = {0.f, 0.f, 0.f, 0.f};

    #pragma unroll 2
    for (int i = 0; i < 8; ++i) {
        const int r = wave * 8 + i, b = r0 + r;
        const float ie = emb_item[(size_t)item_id[b] * DD + lane];
        const int* grow = tmdb_genres + (size_t)b * GG;
        float gacc = 0.f, gw = 0.f;
        #pragma unroll
        for (int g = 0; g < GG; ++g) {
            const int idx = grow[g];
            const float m = (idx > 0) ? 1.f : 0.f;
            gacc = fmaf(m, emb_genre[idx * DD + lane], gacc);
            gw += m;
        }
        const float ig = gacc / (gw + 1e-8f);
        float ic = fmaf(rel_year[b], it_cont_w[lane * 3 + 0],
                   fmaf(i_avg[b],   it_cont_w[lane * 3 + 1],
                   fmaf(revenue[b], it_cont_w[lane * 3 + 2], it_cont_b[lane])));
        ic = fmaxf(ic, 0.f);
        PUT_FRAG(sXf, 6, r, lane, ie);
        PUT_FRAG(sXf, 6, r, 64 + lane, ig);
        PUT_FRAG(sXf, 6, r, 128 + lane, ic);
    }
    __syncthreads();

    f4v acc[2][2];
    #pragma unroll
    for (int a2 = 0; a2 < 2; ++a2)
        #pragma unroll
        for (int c = 0; c < 2; ++c) acc[a2][c] = zero4;
    #pragma unroll
    for (int ks = 0; ks < 6; ++ks) {
        s8v av[2], bv[2];
        #pragma unroll
        for (int ml = 0; ml < 2; ++ml)
            av[ml] = *(const s8v*)&sXf[(((mh * 2 + ml) * 6 + ks) * 64 + lane) * 8];
        #pragma unroll
        for (int nl = 0; nl < 2; ++nl)
            bv[nl] = *(const s8v*)&wblob[(5120 + (ks * 8 + nh * 2 + nl) * 64 + lane) * 8];
        #pragma unroll
        for (int ml = 0; ml < 2; ++ml)
            #pragma unroll
            for (int nl = 0; nl < 2; ++nl)
                acc[ml][nl] = __builtin_amdgcn_mfma_f32_16x16x32_bf16(av[ml], bv[nl], acc[ml][nl], 0, 0, 0);
    }
    __syncthreads();

    #pragma unroll
    for (int ml = 0; ml < 2; ++ml) {
        #pragma unroll
        for (int nl = 0; nl < 2; ++nl) {
            const int n = (nh * 2 + nl) * 16 + (lane & 15);
            const float bb = it_b1[n];
            #pragma unroll
            for (int rg = 0; rg < 4; ++rg) {
                const int m = (mh * 2 + ml) * 16 + (lane >> 4) * 4 + rg;
                sY[m * 128 + n] = acc[ml][nl][rg] + bb;
            }
        }
    }
    __syncthreads();

    {
        const float g0 = it_g[lane], g1 = it_g[lane + 64];
        const float e0 = it_be[lane], e1 = it_be[lane + 64];
        for (int i = 0; i < 8; ++i) {
            const int r = wave * 8 + i;
            const float a = sY[r * 128 + lane];
            const float c = sY[r * 128 + 64 + lane];
            const float mean = wave_reduce_sum(a + c) * (1.f / 128.f);
            const float da = a - mean, dc = c - mean;
            const float var = wave_reduce_sum(da * da + dc * dc) * (1.f / 128.f);
            const float rstd = rsqrtf(var + 1e-5f);
            const float h0 = fmaxf(fmaf(da * rstd, g0, e0), 0.f);
            const float h1 = fmaxf(fmaf(dc * rstd, g1, e1), 0.f);
            PUT_FRAG(sHf, 4, r, lane, h0);
            PUT_FRAG(sHf, 4, r, 64 + lane, h1);
        }
    }
    __syncthreads();

    f4v acc2[2];
    acc2[0] = zero4; acc2[1] = zero4;
    #pragma unroll
    for (int ks = 0; ks < 4; ++ks) {
        s8v av[2], bv;
        #pragma unroll
        for (int ml = 0; ml < 2; ++ml)
            av[ml] = *(const s8v*)&sHf[(((mh * 2 + ml) * 4 + ks) * 64 + lane) * 8];
        bv = *(const s8v*)&wblob[(8192 + (ks * 4 + nh) * 64 + lane) * 8];
        #pragma unroll
        for (int ml = 0; ml < 2; ++ml)
            acc2[ml] = __builtin_amdgcn_mfma_f32_16x16x32_bf16(av[ml], bv, acc2[ml], 0, 0, 0);
    }
    #pragma unroll
    for (int ml = 0; ml < 2; ++ml) {
        const int n = nh * 16 + (lane & 15);
        const float bb = it_b2[n];
        #pragma unroll
        for (int rg = 0; rg < 4; ++rg) {
            const int m = (mh * 2 + ml) * 16 + (lane >> 4) * 4 + rg;
            sO[m * 64 + n] = acc2[ml][rg] + bb;
        }
    }
    __syncthreads();

    for (int i = 0; i < 8; ++i) {
        const int r = wave * 8 + i;
        const float o = sO[r * 64 + lane];
        const float nrm = sqrtf(wave_reduce_sum(o * o));
        out[(size_t)B * DD + (size_t)(r0 + r) * DD + lane] = o / fmaxf(nrm, 1e-12f);
    }
}

//======================================================================
// Kernel 2: user tower (256 -> 128 -> 64), 64 rows/block, 8 waves.
//======================================================================
__global__ __launch_bounds__(512, 4)
void user_tower_kernel(
    const int* __restrict__ user_id, const int* __restrict__ top_genres,
    const float* __restrict__ hist_pool,
    const float* __restrict__ u_avg, const float* __restrict__ activity,
    const float* __restrict__ emb_genre, const float* __restrict__ emb_user,
    const float* __restrict__ cont_w, const float* __restrict__ cont_b,
    const unsigned short* __restrict__ wblob,
    const float* __restrict__ b1, const float* __restrict__ gam,
    const float* __restrict__ bet, const float* __restrict__ b2,
    float* __restrict__ out, int B)
{
    const int tid = threadIdx.x, wave = tid >> 6, lane = tid & 63;
    const int r0 = blockIdx.x * 64;

    __shared__ __align__(16) unsigned char  sC[64 * 128 * 4];     // 32KB: Xfrag -> y -> o
    __shared__ __align__(16) unsigned short sHf[4 * 4 * 64 * 8];  // 16KB

    unsigned short* sXf = (unsigned short*)sC;
    float* sY = (float*)sC;
    float* sO = (float*)sC;

    const int mh = wave >> 2, nh = wave & 3;
    const f4v zero4 = {0.f, 0.f, 0.f, 0.f};

    #pragma unroll 2
    for (int i = 0; i < 8; ++i) {
        const int r = wave * 8 + i, b = r0 + r;
        const float ue = emb_user[(size_t)user_id[b] * DD + lane];
        const float hp = hist_pool[(size_t)b * DD + lane];
        const int* grow = top_genres + (size_t)b * GG;
        float gacc = 0.f, gw = 0.f;
        #pragma unroll
        for (int g = 0; g < GG; ++g) {
            const int idx = grow[g];
            const float m = (idx > 0) ? 1.f : 0.f;
            gacc = fmaf(m, emb_genre[idx * DD + lane], gacc);
            gw += m;
        }
        const float ug = gacc / (gw + 1e-8f);
        float uc = fmaf(u_avg[b], cont_w[lane * 2 + 0],
                   fmaf(activity[b], cont_w[lane * 2 + 1], cont_b[lane]));
        uc = fmaxf(uc, 0.f);
        PUT_FRAG(sXf, 8, r, lane, ue);
        PUT_FRAG(sXf, 8, r, 64 + lane, hp);
        PUT_FRAG(sXf, 8, r, 128 + lane, ug);
        PUT_FRAG(sXf, 8, r, 192 + lane, uc);
    }
    __syncthreads();

    f4v acc[2][2];
    #pragma unroll
    for (int a = 0; a < 2; ++a)
        #pragma unroll
        for (int c = 0; c < 2; ++c) acc[a][c] = zero4;
    #pragma unroll
    for (int ks = 0; ks < 8; ++ks) {
        s8v av[2], bv[2];
        #pragma unroll
        for (int ml = 0; ml < 2; ++ml)
            av[ml] = *(const s8v*)&sXf[(((mh * 2 + ml) * 8 + ks) * 64 + lane) * 8];
        #pragma unroll
        for (int nl = 0; nl < 2; ++nl)
            bv[nl] = *(const s8v*)&wblob[((ks * 8 + nh * 2 + nl) * 64 + lane) * 8];
        #pragma unroll
        for (int ml = 0; ml < 2; ++ml)
            #pragma unroll
            for (int nl = 0; nl < 2; ++nl)
                acc[ml][nl] = __builtin_amdgcn_mfma_f32_16x16x32_bf16(av[ml], bv[nl], acc[ml][nl], 0, 0, 0);
    }
    __syncthreads();

    #pragma unroll
    for (int ml = 0; ml < 2; ++ml) {
        #pragma unroll
        for (int nl = 0; nl < 2; ++nl) {
            const int n = (nh * 2 + nl) * 16 + (lane & 15);
            const float bb = b1[n];
            #pragma unroll
            for (int rg = 0; rg < 4; ++rg) {
                const int m = (mh * 2 + ml) * 16 + (lane >> 4) * 4 + rg;
                sY[m * 128 + n] = acc[ml][nl][rg] + bb;
            }
        }
    }
    __syncthreads();

    {
        const float g0 = gam[lane], g1 = gam[lane + 64];
        const float e0 = bet[lane], e1 = bet[lane + 64];
        for (int i = 0; i < 8; ++i) {
            const int r = wave * 8 + i;
            const float a = sY[r * 128 + lane];
            const float c = sY[r * 128 + 64 + lane];
            const float mean = wave_reduce_sum(a + c) * (1.f / 128.f);
            const float da = a - mean, dc = c - mean;
            const float var = wave_reduce_sum(da * da + dc * dc) * (1.f / 128.f);
            const float rstd = rsqrtf(var + 1e-5f);
            const float h0 = fmaxf(fmaf(da * rstd, g0, e0), 0.f);
            const float h1 = fmaxf(fmaf(dc * rstd, g1, e1), 0.f);
            PUT_FRAG(sHf, 4, r, lane, h0);
            PUT_FRAG(sHf, 4, r, 64 + lane, h1);
        }
    }
    __syncthreads();

    f4v acc2[2];
    acc2[0] = zero4; acc2[1] = zero4;
    #pragma unroll
    for (int ks = 0; ks < 4; ++ks) {
        s8v av[2], bv;
        #pragma unroll
        for (int ml = 0; ml < 2; ++ml)
            av[ml] = *(const s8v*)&sHf[(((mh * 2 + ml) * 4 + ks) * 64 + lane) * 8];
        bv = *(const s8v*)&wblob[(4096 + (ks * 4 + nh) * 64 + lane) * 8];
        #pragma unroll
        for (int ml = 0; ml < 2; ++ml)
            acc2[ml] = __builtin_amdgcn_mfma_f32_16x16x32_bf16(av[ml], bv, acc2[ml], 0, 0, 0);
    }
    #pragma unroll
    for (int ml = 0; ml < 2; ++ml) {
        const int n = nh * 16 + (lane & 15);
        const float bb = b2[n];
        #pragma unroll
        for (int rg = 0; rg < 4; ++rg) {
            const int m = (mh * 2 + ml) * 16 + (lane >> 4) * 4 + rg;
            sO[m * 64 + n] = acc2[ml][rg] + bb;
        }
    }
    __syncthreads();

    for (int i = 0; i < 8; ++i) {
        const int r = wave * 8 + i;
        const float o = sO[r * 64 + lane];
        const float nrm = sqrtf(wave_reduce_sum(o * o));
        out[(size_t)(r0 + r) * DD + lane] = o / fmaxf(nrm, 1e-12f);
    }
}

extern "C" void kernel_launch(void* const* d_in, const int* in_sizes, int n_in,
                              void* d_out, int out_size, void* d_ws, size_t ws_size,
                              hipStream_t stream) {
    const int*   user_id     = (const int*)  d_in[0];
    const int*   history     = (const int*)  d_in[1];
    const int*   top_genres  = (const int*)  d_in[2];
    const int*   item_id     = (const int*)  d_in[3];
    const int*   tmdb_genres = (const int*)  d_in[4];
    const float* ts_diff     = (const float*)d_in[5];
    const float* u_avg       = (const float*)d_in[6];
    const float* activity    = (const float*)d_in[7];
    const float* rel_year    = (const float*)d_in[8];
    const float* i_avg       = (const float*)d_in[9];
    const float* revenue     = (const float*)d_in[10];
    const float* emb_item    = (const float*)d_in[11];
    const float* emb_genre   = (const float*)d_in[12];
    const float* emb_user    = (const float*)d_in[13];
    const float* ut_cont_w   = (const float*)d_in[14];
    const float* ut_cont_b   = (const float*)d_in[15];
    const float* ut_w1       = (const float*)d_in[16];
    const float* ut_b1       = (const float*)d_in[17];
    const float* ut_g        = (const float*)d_in[18];
    const float* ut_be       = (const float*)d_in[19];
    const float* ut_w2       = (const float*)d_in[20];
    const float* ut_b2       = (const float*)d_in[21];
    const float* it_cont_w   = (const float*)d_in[22];
    const float* it_cont_b   = (const float*)d_in[23];
    const float* it_w1       = (const float*)d_in[24];
    const float* it_b1       = (const float*)d_in[25];
    const float* it_g        = (const float*)d_in[26];
    const float* it_be       = (const float*)d_in[27];
    const float* it_w2       = (const float*)d_in[28];
    const float* it_b2       = (const float*)d_in[29];

    const int B = in_sizes[0];                 // 16384
    const int n_item = in_sizes[11];           // V_ITEM * 64

    // workspace layout
    unsigned int* emb8 = (unsigned int*)d_ws;                         // 6.4MB
    size_t off = (size_t)(n_item / 4) * sizeof(unsigned int);
    off = (off + 255) & ~(size_t)255;
    unsigned short* wblob = (unsigned short*)((char*)d_ws + off);     // 144KB
    off += (size_t)9216 * 8 * sizeof(unsigned short);
    off = (off + 255) & ~(size_t)255;
    float* hist_pool = (float*)((char*)d_ws + off);                   // 4MB

    hipLaunchKernelGGL(prep_kernel, dim3(FP8_BLOCKS + 36), dim3(256), 0, stream,
        emb_item, ut_w1, ut_w2, it_w1, it_w2, emb8, wblob, n_item / 8);

    hipLaunchKernelGGL(hist_item_kernel, dim3(B / 64 + B / 8), dim3(512), 0, stream,
        item_id, tmdb_genres, history, ts_diff, (const uint2*)emb8,
        rel_year, i_avg, revenue,
        emb_item, emb_genre, it_cont_w, it_cont_b,
        wblob, it_b1, it_g, it_be, it_b2,
        hist_pool, (float*)d_out, B);

    hipLaunchKernelGGL(user_tower_kernel, dim3(B / 64), dim3(512), 0, stream,
        user_id, top_genres, hist_pool, u_avg, activity,
        emb_genre, emb_user, ut_cont_w, ut_cont_b,
        wblob, ut_b1, ut_g, ut_be, ut_b2,
        (float*)d_out, B);
}

// Round 12
// 73.822 us; speedup vs baseline: 1.3398x; 1.0309x over previous
//
#include <hip/hip_runtime.h>

#define DD 64
#define LL 200
#define LP 256     // LL padded
#define GG 6
#define LAMBDA 0.001f
#define FP8_BLOCKS 3126   // ceil(100001*64/8 / 256)

typedef __attribute__((ext_vector_type(8))) short s8v;   // 8 bf16 (4 VGPRs)
typedef __attribute__((ext_vector_type(4))) float f4v;   // MFMA accumulator
typedef __attribute__((ext_vector_type(2))) float f2v;

__device__ __forceinline__ float wave_reduce_sum(float v) {
    #pragma unroll
    for (int off = 32; off > 0; off >>= 1)
        v += __shfl_xor(v, off, 64);
    return v;
}

__device__ __forceinline__ unsigned short f2bf(float f) {
    union { float f; unsigned int u; } v; v.f = f;
    return (unsigned short)((v.u + 0x7FFFu + ((v.u >> 16) & 1u)) >> 16);  // RNE
}

//======================================================================
// Kernel 0: fused prep.
//  blocks [0, FP8_BLOCKS): emb_item fp32 -> fp8 e4m3 (x64 scale) table
//  blocks [FP8_BLOCKS, +36): 4 MLP weight matrices -> frag-order bf16 blob
//======================================================================
__global__ __launch_bounds__(256)
void prep_kernel(const float* __restrict__ emb_item,
                 const float* __restrict__ ut_w1, const float* __restrict__ ut_w2,
                 const float* __restrict__ it_w1, const float* __restrict__ it_w2,
                 unsigned int* __restrict__ emb8,
                 unsigned short* __restrict__ blob, int n8)
{
    if (blockIdx.x < FP8_BLOCKS) {
        const int i = blockIdx.x * 256 + threadIdx.x;
        if (i < n8) {
            const float4 f0 = *(const float4*)&emb_item[(size_t)i * 8];
            const float4 f1 = *(const float4*)&emb_item[(size_t)i * 8 + 4];
            int lo = __builtin_amdgcn_cvt_pk_fp8_f32(f0.x * 64.f, f0.y * 64.f, 0, false);
            lo     = __builtin_amdgcn_cvt_pk_fp8_f32(f0.z * 64.f, f0.w * 64.f, lo, true);
            int hi = __builtin_amdgcn_cvt_pk_fp8_f32(f1.x * 64.f, f1.y * 64.f, 0, false);
            hi     = __builtin_amdgcn_cvt_pk_fp8_f32(f1.z * 64.f, f1.w * 64.f, hi, true);
            uint2 o; o.x = (unsigned int)lo; o.y = (unsigned int)hi;
            *(uint2*)&emb8[(size_t)i * 2] = o;
        }
        return;
    }
    const int s = (blockIdx.x - FP8_BLOCKS) * 256 + threadIdx.x;   // 0..9215
    if (s >= 9216) return;
    const float* src; int K, NT, r, k8; size_t obase;
    if (s < 4096)      { src = ut_w1; K = 256; NT = 8; r = s >> 5;          k8 = s & 31;          obase = 0; }
    else if (s < 5120) { src = ut_w2; K = 128; NT = 4; r = (s-4096) >> 4;   k8 = (s-4096) & 15;   obase = 4096; }
    else if (s < 8192) { src = it_w1; K = 192; NT = 8; r = (s-5120) / 24;   k8 = (s-5120) % 24;   obase = 5120; }
    else               { src = it_w2; K = 128; NT = 4; r = (s-8192) >> 4;   k8 = (s-8192) & 15;   obase = 8192; }
    const int k = k8 * 8;
    const float4 f0 = *(const float4*)&src[(size_t)r * K + k];
    const float4 f1 = *(const float4*)&src[(size_t)r * K + k + 4];
    const int ks = k >> 5, lg = (k >> 3) & 3;
    const int lp = lg * 16 + (r & 15), nt = r >> 4;
    const size_t slot = obase + (size_t)(ks * NT + nt) * 64 + lp;
    s8v wv;
    wv[0]=(short)f2bf(f0.x); wv[1]=(short)f2bf(f0.y); wv[2]=(short)f2bf(f0.z); wv[3]=(short)f2bf(f0.w);
    wv[4]=(short)f2bf(f1.x); wv[5]=(short)f2bf(f1.y); wv[6]=(short)f2bf(f1.z); wv[7]=(short)f2bf(f1.w);
    *(s8v*)&blob[slot * 8] = wv;
}

//======================================================================
// X/H fragment slot: A-operand layout for mfma_f32_16x16x32_bf16
//======================================================================
#define PUT_FRAG(buf, NKS, r, d, val)                                   \
    do {                                                                \
        const int _mt = (r) >> 4, _ks = (d) >> 5;                       \
        const int _lp = (((d) >> 3) & 3) * 16 + ((r) & 15);             \
        (buf)[(((_mt) * (NKS) + _ks) * 64 + _lp) * 8 + ((d) & 7)] = f2bf(val); \
    } while (0)

//======================================================================
// Kernel 1: item tower M=32 (blocks [0, B/32)) + hist (blocks [B/32,..)).
// 16KB LDS total -> hist occupancy is VGPR-limited, not LDS-limited.
//======================================================================
__global__ __launch_bounds__(512)
void hist_item_kernel(
    const int* __restrict__ item_id, const int* __restrict__ tmdb_genres,
    const int* __restrict__ history, const float* __restrict__ ts_diff,
    const uint2* __restrict__ emb8,
    const float* __restrict__ rel_year, const float* __restrict__ i_avg,
    const float* __restrict__ revenue,
    const float* __restrict__ emb_item, const float* __restrict__ emb_genre,
    const float* __restrict__ it_cont_w, const float* __restrict__ it_cont_b,
    const unsigned short* __restrict__ wblob,
    const float* __restrict__ it_b1, const float* __restrict__ it_g,
    const float* __restrict__ it_be, const float* __restrict__ it_b2,
    float* __restrict__ hist_pool, float* __restrict__ out, int B)
{
    const int tid = threadIdx.x, wave = tid >> 6, lane = tid & 63;
    const int nI = B / 32;

    __shared__ __align__(16) unsigned char smem[16 * 1024];

    if ((int)blockIdx.x >= nI) {
        //================= history pooling: 8 waves x 1 row =================
        const int b = ((int)blockIdx.x - nI) * 8 + wave;
        const int grp = lane >> 3;
        const int c8 = lane & 7;
        float2* sp = (float2*)smem + wave * LP;   // wave-private 2KB

        const int*   hrow = history + (size_t)b * LL;
        const float* trow = ts_diff + (size_t)b * LL;

        float wpart = 0.f;
        #pragma unroll
        for (int l = lane; l < LP; l += 64) {
            int idx = 0; float w = 0.f;
            if (l < LL) {
                const int raw = hrow[l];
                if (raw > 0) { w = __expf(-LAMBDA * trow[l]); idx = raw; }
            }
            sp[l] = make_float2(w, __int_as_float(idx));
            wpart += w;
        }
        const float wsum = wave_reduce_sum(wpart);

        float a[8];
        #pragma unroll
        for (int j = 0; j < 8; ++j) a[j] = 0.f;

        #pragma unroll 1
        for (int l0 = 0; l0 < LP; l0 += 128) {
            uint2 e[16]; float w[16];
            #pragma unroll
            for (int i = 0; i < 16; ++i) {
                const float2 p = sp[l0 + i * 8 + grp];
                w[i] = p.x;
                e[i] = emb8[(size_t)__float_as_int(p.y) * 8 + c8];
            }
            #pragma unroll
            for (int i = 0; i < 16; ++i) {
                const f2v d01 = __builtin_amdgcn_cvt_pk_f32_fp8((int)e[i].x, false);
                const f2v d23 = __builtin_amdgcn_cvt_pk_f32_fp8((int)e[i].x, true);
                const f2v d45 = __builtin_amdgcn_cvt_pk_f32_fp8((int)e[i].y, false);
                const f2v d67 = __builtin_amdgcn_cvt_pk_f32_fp8((int)e[i].y, true);
                a[0] = fmaf(w[i], d01[0], a[0]);
                a[1] = fmaf(w[i], d01[1], a[1]);
                a[2] = fmaf(w[i], d23[0], a[2]);
                a[3] = fmaf(w[i], d23[1], a[3]);
                a[4] = fmaf(w[i], d45[0], a[4]);
                a[5] = fmaf(w[i], d45[1], a[5]);
                a[6] = fmaf(w[i], d67[0], a[6]);
                a[7] = fmaf(w[i], d67[1], a[7]);
            }
        }
        #pragma unroll
        for (int off = 8; off <= 32; off <<= 1)
            #pragma unroll
            for (int j = 0; j < 8; ++j)
                a[j] += __shfl_xor(a[j], off, 64);

        if (grp == 0) {
            const float inv = 0.015625f / (wsum + 1e-8f);
            float4 o0 = make_float4(a[0]*inv, a[1]*inv, a[2]*inv, a[3]*inv);
            float4 o1 = make_float4(a[4]*inv, a[5]*inv, a[6]*inv, a[7]*inv);
            *(float4*)&hist_pool[(size_t)b * DD + c8 * 8]     = o0;
            *(float4*)&hist_pool[(size_t)b * DD + c8 * 8 + 4] = o1;
        }
        return;
    }

    //================= item tower, M=32 rows/block =================
    const int r0 = blockIdx.x * 32;
    unsigned short* sXf = (unsigned short*)smem;           // 12KB
    float* sY = (float*)smem;                              // 16KB (alias)
    unsigned short* sHf = (unsigned short*)smem;           // 8KB (alias)
    float* sO = (float*)(smem + 8 * 1024);                 // 8KB

    const int mh = wave >> 2, nh = wave & 3;
    const f4v zero4 = {0.f, 0.f, 0.f, 0.f};

    //---- build X features: 8 waves x 4 rows ----
    #pragma unroll
    for (int i = 0; i < 4; ++i) {
        const int r = wave * 4 + i, b = r0 + r;
        const float ie = emb_item[(size_t)item_id[b] * DD + lane];
        const int* grow = tmdb_genres + (size_t)b * GG;
        float gacc = 0.f, gw = 0.f;
        #pragma unroll
        for (int g = 0; g < GG; ++g) {
            const int idx = grow[g];
            const float m = (idx > 0) ? 1.f : 0.f;
            gacc = fmaf(m, emb_genre[idx * DD + lane], gacc);
            gw += m;
        }
        const float ig = gacc / (gw + 1e-8f);
        float ic = fmaf(rel_year[b], it_cont_w[lane * 3 + 0],
                   fmaf(i_avg[b],   it_cont_w[lane * 3 + 1],
                   fmaf(revenue[b], it_cont_w[lane * 3 + 2], it_cont_b[lane])));
        ic = fmaxf(ic, 0.f);
        PUT_FRAG(sXf, 6, r, lane, ie);
        PUT_FRAG(sXf, 6, r, 64 + lane, ig);
        PUT_FRAG(sXf, 6, r, 128 + lane, ic);
    }
    __syncthreads();

    //---- L1 MFMA: M=32, N=128, K=192; wave = (mh mtile, nh ntile-pair) ----
    f4v acc[2];
    acc[0] = zero4; acc[1] = zero4;
    #pragma unroll
    for (int ks = 0; ks < 6; ++ks) {
        const s8v av = *(const s8v*)&sXf[((mh * 6 + ks) * 64 + lane) * 8];
        #pragma unroll
        for (int nl = 0; nl < 2; ++nl) {
            const s8v bv = *(const s8v*)&wblob[(5120 + (ks * 8 + nh * 2 + nl) * 64 + lane) * 8];
            acc[nl] = __builtin_amdgcn_mfma_f32_16x16x32_bf16(av, bv, acc[nl], 0, 0, 0);
        }
    }
    __syncthreads();   // all waves done reading sXf

    //---- y = acc + b1 -> sY [32][128] fp32 ----
    #pragma unroll
    for (int nl = 0; nl < 2; ++nl) {
        const int n = (nh * 2 + nl) * 16 + (lane & 15);
        const float bb = it_b1[n];
        #pragma unroll
        for (int rg = 0; rg < 4; ++rg) {
            const int m = mh * 16 + (lane >> 4) * 4 + rg;
            sY[m * 128 + n] = acc[nl][rg] + bb;
        }
    }
    __syncthreads();

    //---- LN + ReLU (results held in regs across the barrier) ----
    float h0[4], h1[4];
    {
        const float g0 = it_g[lane], g1 = it_g[lane + 64];
        const float e0 = it_be[lane], e1 = it_be[lane + 64];
        #pragma unroll
        for (int i = 0; i < 4; ++i) {
            const int r = wave * 4 + i;
            const float a = sY[r * 128 + lane];
            const float c = sY[r * 128 + 64 + lane];
            const float mean = wave_reduce_sum(a + c) * (1.f / 128.f);
            const float da = a - mean, dc = c - mean;
            const float var = wave_reduce_sum(da * da + dc * dc) * (1.f / 128.f);
            const float rstd = rsqrtf(var + 1e-5f);
            h0[i] = fmaxf(fmaf(da * rstd, g0, e0), 0.f);
            h1[i] = fmaxf(fmaf(dc * rstd, g1, e1), 0.f);
        }
    }
    __syncthreads();   // everyone done reading sY; safe to overwrite with sHf
    #pragma unroll
    for (int i = 0; i < 4; ++i) {
        const int r = wave * 4 + i;
        PUT_FRAG(sHf, 4, r, lane, h0[i]);
        PUT_FRAG(sHf, 4, r, 64 + lane, h1[i]);
    }
    __syncthreads();

    //---- L2 MFMA: M=32, N=64, K=128 ----
    f4v acc2 = zero4;
    #pragma unroll
    for (int ks = 0; ks < 4; ++ks) {
        const s8v av = *(const s8v*)&sHf[((mh * 4 + ks) * 64 + lane) * 8];
        const s8v bv = *(const s8v*)&wblob[(8192 + (ks * 4 + nh) * 64 + lane) * 8];
        acc2 = __builtin_amdgcn_mfma_f32_16x16x32_bf16(av, bv, acc2, 0, 0, 0);
    }
    {
        const int n = nh * 16 + (lane & 15);
        const float bb = it_b2[n];
        #pragma unroll
        for (int rg = 0; rg < 4; ++rg) {
            const int m = mh * 16 + (lane >> 4) * 4 + rg;
            sO[m * 64 + n] = acc2[rg] + bb;     // sO disjoint from sHf
        }
    }
    __syncthreads();

    //---- l2norm + store ----
    #pragma unroll
    for (int i = 0; i < 4; ++i) {
        const int r = wave * 4 + i;
        const float o = sO[r * 64 + lane];
        const float nrm = sqrtf(wave_reduce_sum(o * o));
        out[(size_t)B * DD + (size_t)(r0 + r) * DD + lane] = o / fmaxf(nrm, 1e-12f);
    }
}

//======================================================================
// Kernel 2: user tower (256 -> 128 -> 64), 64 rows/block, 8 waves.
//======================================================================
__global__ __launch_bounds__(512)
void user_tower_kernel(
    const int* __restrict__ user_id, const int* __restrict__ top_genres,
    const float* __restrict__ hist_pool,
    const float* __restrict__ u_avg, const float* __restrict__ activity,
    const float* __restrict__ emb_genre, const float* __restrict__ emb_user,
    const float* __restrict__ cont_w, const float* __restrict__ cont_b,
    const unsigned short* __restrict__ wblob,
    const float* __restrict__ b1, const float* __restrict__ gam,
    const float* __restrict__ bet, const float* __restrict__ b2,
    float* __restrict__ out, int B)
{
    const int tid = threadIdx.x, wave = tid >> 6, lane = tid & 63;
    const int r0 = blockIdx.x * 64;

    __shared__ __align__(16) unsigned char  sC[64 * 128 * 4];     // 32KB
    __shared__ __align__(16) unsigned short sHf[4 * 4 * 64 * 8];  // 16KB

    unsigned short* sXf = (unsigned short*)sC;
    float* sY = (float*)sC;
    float* sO = (float*)sC;

    const int mh = wave >> 2, nh = wave & 3;
    const f4v zero4 = {0.f, 0.f, 0.f, 0.f};

    #pragma unroll 2
    for (int i = 0; i < 8; ++i) {
        const int r = wave * 8 + i, b = r0 + r;
        const float ue = emb_user[(size_t)user_id[b] * DD + lane];
        const float hp = hist_pool[(size_t)b * DD + lane];
        const int* grow = top_genres + (size_t)b * GG;
        float gacc = 0.f, gw = 0.f;
        #pragma unroll
        for (int g = 0; g < GG; ++g) {
            const int idx = grow[g];
            const float m = (idx > 0) ? 1.f : 0.f;
            gacc = fmaf(m, emb_genre[idx * DD + lane], gacc);
            gw += m;
        }
        const float ug = gacc / (gw + 1e-8f);
        float uc = fmaf(u_avg[b], cont_w[lane * 2 + 0],
                   fmaf(activity[b], cont_w[lane * 2 + 1], cont_b[lane]));
        uc = fmaxf(uc, 0.f);
        PUT_FRAG(sXf, 8, r, lane, ue);
        PUT_FRAG(sXf, 8, r, 64 + lane, hp);
        PUT_FRAG(sXf, 8, r, 128 + lane, ug);
        PUT_FRAG(sXf, 8, r, 192 + lane, uc);
    }
    __syncthreads();

    f4v acc[2][2];
    #pragma unroll
    for (int a = 0; a < 2; ++a)
        #pragma unroll
        for (int c = 0; c < 2; ++c) acc[a][c] = zero4;
    #pragma unroll
    for (int ks = 0; ks < 8; ++ks) {
        s8v av[2], bv[2];
        #pragma unroll
        for (int ml = 0; ml < 2; ++ml)
            av[ml] = *(const s8v*)&sXf[(((mh * 2 + ml) * 8 + ks) * 64 + lane) * 8];
        #pragma unroll
        for (int nl = 0; nl < 2; ++nl)
            bv[nl] = *(const s8v*)&wblob[((ks * 8 + nh * 2 + nl) * 64 + lane) * 8];
        #pragma unroll
        for (int ml = 0; ml < 2; ++ml)
            #pragma unroll
            for (int nl = 0; nl < 2; ++nl)
                acc[ml][nl] = __builtin_amdgcn_mfma_f32_16x16x32_bf16(av[ml], bv[nl], acc[ml][nl], 0, 0, 0);
    }
    __syncthreads();

    #pragma unroll
    for (int ml = 0; ml < 2; ++ml) {
        #pragma unroll
        for (int nl = 0; nl < 2; ++nl) {
            const int n = (nh * 2 + nl) * 16 + (lane & 15);
            const float bb = b1[n];
            #pragma unroll
            for (int rg = 0; rg < 4; ++rg) {
                const int m = (mh * 2 + ml) * 16 + (lane >> 4) * 4 + rg;
                sY[m * 128 + n] = acc[ml][nl][rg] + bb;
            }
        }
    }
    __syncthreads();

    {
        const float g0 = gam[lane], g1 = gam[lane + 64];
        const float e0 = bet[lane], e1 = bet[lane + 64];
        for (int i = 0; i < 8; ++i) {
            const int r = wave * 8 + i;
            const float a = sY[r * 128 + lane];
            const float c = sY[r * 128 + 64 + lane];
            const float mean = wave_reduce_sum(a + c) * (1.f / 128.f);
            const float da = a - mean, dc = c - mean;
            const float var = wave_reduce_sum(da * da + dc * dc) * (1.f / 128.f);
            const float rstd = rsqrtf(var + 1e-5f);
            const float h0 = fmaxf(fmaf(da * rstd, g0, e0), 0.f);
            const float h1 = fmaxf(fmaf(dc * rstd, g1, e1), 0.f);
            PUT_FRAG(sHf, 4, r, lane, h0);
            PUT_FRAG(sHf, 4, r, 64 + lane, h1);
        }
    }
    __syncthreads();

    f4v acc2[2];
    acc2[0] = zero4; acc2[1] = zero4;
    #pragma unroll
    for (int ks = 0; ks < 4; ++ks) {
        s8v av[2], bv;
        #pragma unroll
        for (int ml = 0; ml < 2; ++ml)
            av[ml] = *(const s8v*)&sHf[(((mh * 2 + ml) * 4 + ks) * 64 + lane) * 8];
        bv = *(const s8v*)&wblob[(4096 + (ks * 4 + nh) * 64 + lane) * 8];
        #pragma unroll
        for (int ml = 0; ml < 2; ++ml)
            acc2[ml] = __builtin_amdgcn_mfma_f32_16x16x32_bf16(av[ml], bv, acc2[ml], 0, 0, 0);
    }
    #pragma unroll
    for (int ml = 0; ml < 2; ++ml) {
        const int n = nh * 16 + (lane & 15);
        const float bb = b2[n];
        #pragma unroll
        for (int rg = 0; rg < 4; ++rg) {
            const int m = (mh * 2 + ml) * 16 + (lane >> 4) * 4 + rg;
            sO[m * 64 + n] = acc2[ml][rg] + bb;
        }
    }
    __syncthreads();

    for (int i = 0; i < 8; ++i) {
        const int r = wave * 8 + i;
        const float o = sO[r * 64 + lane];
        const float nrm = sqrtf(wave_reduce_sum(o * o));
        out[(size_t)(r0 + r) * DD + lane] = o / fmaxf(nrm, 1e-12f);
    }
}

extern "C" void kernel_launch(void* const* d_in, const int* in_sizes, int n_in,
                              void* d_out, int out_size, void* d_ws, size_t ws_size,
                              hipStream_t stream) {
    const int*   user_id     = (const int*)  d_in[0];
    const int*   history     = (const int*)  d_in[1];
    const int*   top_genres  = (const int*)  d_in[2];
    const int*   item_id     = (const int*)  d_in[3];
    const int*   tmdb_genres = (const int*)  d_in[4];
    const float* ts_diff     = (const float*)d_in[5];
    const float* u_avg       = (const float*)d_in[6];
    const float* activity    = (const float*)d_in[7];
    const float* rel_year    = (const float*)d_in[8];
    const float* i_avg       = (const float*)d_in[9];
    const float* revenue     = (const float*)d_in[10];
    const float* emb_item    = (const float*)d_in[11];
    const float* emb_genre   = (const float*)d_in[12];
    const float* emb_user    = (const float*)d_in[13];
    const float* ut_cont_w   = (const float*)d_in[14];
    const float* ut_cont_b   = (const float*)d_in[15];
    const float* ut_w1       = (const float*)d_in[16];
    const float* ut_b1       = (const float*)d_in[17];
    const float* ut_g        = (const float*)d_in[18];
    const float* ut_be       = (const float*)d_in[19];
    const float* ut_w2       = (const float*)d_in[20];
    const float* ut_b2       = (const float*)d_in[21];
    const float* it_cont_w   = (const float*)d_in[22];
    const float* it_cont_b   = (const float*)d_in[23];
    const float* it_w1       = (const float*)d_in[24];
    const float* it_b1       = (const float*)d_in[25];
    const float* it_g        = (const float*)d_in[26];
    const float* it_be       = (const float*)d_in[27];
    const float* it_w2       = (const float*)d_in[28];
    const float* it_b2       = (const float*)d_in[29];

    const int B = in_sizes[0];                 // 16384
    const int n_item = in_sizes[11];           // V_ITEM * 64

    // workspace layout
    unsigned int* emb8 = (unsigned int*)d_ws;                         // 6.4MB
    size_t off = (size_t)(n_item / 4) * sizeof(unsigned int);
    off = (off + 255) & ~(size_t)255;
    unsigned short* wblob = (unsigned short*)((char*)d_ws + off);     // 144KB
    off += (size_t)9216 * 8 * sizeof(unsigned short);
    off = (off + 255) & ~(size_t)255;
    float* hist_pool = (float*)((char*)d_ws + off);                   // 4MB

    hipLaunchKernelGGL(prep_kernel, dim3(FP8_BLOCKS + 36), dim3(256), 0, stream,
        emb_item, ut_w1, ut_w2, it_w1, it_w2, emb8, wblob, n_item / 8);

    hipLaunchKernelGGL(hist_item_kernel, dim3(B / 32 + B / 8), dim3(512), 0, stream,
        item_id, tmdb_genres, history, ts_diff, (const uint2*)emb8,
        rel_year, i_avg, revenue,
        emb_item, emb_genre, it_cont_w, it_cont_b,
        wblob, it_b1, it_g, it_be, it_b2,
        hist_pool, (float*)d_out, B);

    hipLaunchKernelGGL(user_tower_kernel, dim3(B / 64), dim3(512), 0, stream,
        user_id, top_genres, hist_pool, u_avg, activity,
        emb_genre, emb_user, ut_cont_w, ut_cont_b,
        wblob, ut_b1, ut_g, ut_be, ut_b2,
        (float*)d_out, B);
}

// Round 13
// 62.643 us; speedup vs baseline: 1.5789x; 1.1785x over previous
//
#include <hip/hip_runtime.h>

#define DD 64
#define LL 200
#define LP 256     // LL padded
#define GG 6
#define LAMBDA 0.001f
#define FP8_BLOCKS 3126   // ceil(100001*64/8 / 256)

typedef __attribute__((ext_vector_type(8))) short s8v;   // 8 bf16 (4 VGPRs)
typedef __attribute__((ext_vector_type(4))) float f4v;   // MFMA accumulator
typedef __attribute__((ext_vector_type(2))) float f2v;

__device__ __forceinline__ float wave_reduce_sum(float v) {
    #pragma unroll
    for (int off = 32; off > 0; off >>= 1)
        v += __shfl_xor(v, off, 64);
    return v;
}

__device__ __forceinline__ unsigned short f2bf(float f) {
    union { float f; unsigned int u; } v; v.f = f;
    return (unsigned short)((v.u + 0x7FFFu + ((v.u >> 16) & 1u)) >> 16);  // RNE
}

//======================================================================
// Kernel 0: fused prep.
//======================================================================
__global__ __launch_bounds__(256)
void prep_kernel(const float* __restrict__ emb_item,
                 const float* __restrict__ ut_w1, const float* __restrict__ ut_w2,
                 const float* __restrict__ it_w1, const float* __restrict__ it_w2,
                 unsigned int* __restrict__ emb8,
                 unsigned short* __restrict__ blob, int n8)
{
    if (blockIdx.x < FP8_BLOCKS) {
        const int i = blockIdx.x * 256 + threadIdx.x;
        if (i < n8) {
            const float4 f0 = *(const float4*)&emb_item[(size_t)i * 8];
            const float4 f1 = *(const float4*)&emb_item[(size_t)i * 8 + 4];
            int lo = __builtin_amdgcn_cvt_pk_fp8_f32(f0.x * 64.f, f0.y * 64.f, 0, false);
            lo     = __builtin_amdgcn_cvt_pk_fp8_f32(f0.z * 64.f, f0.w * 64.f, lo, true);
            int hi = __builtin_amdgcn_cvt_pk_fp8_f32(f1.x * 64.f, f1.y * 64.f, 0, false);
            hi     = __builtin_amdgcn_cvt_pk_fp8_f32(f1.z * 64.f, f1.w * 64.f, hi, true);
            uint2 o; o.x = (unsigned int)lo; o.y = (unsigned int)hi;
            *(uint2*)&emb8[(size_t)i * 2] = o;
        }
        return;
    }
    const int s = (blockIdx.x - FP8_BLOCKS) * 256 + threadIdx.x;   // 0..9215
    if (s >= 9216) return;
    const float* src; int K, NT, r, k8; size_t obase;
    if (s < 4096)      { src = ut_w1; K = 256; NT = 8; r = s >> 5;          k8 = s & 31;          obase = 0; }
    else if (s < 5120) { src = ut_w2; K = 128; NT = 4; r = (s-4096) >> 4;   k8 = (s-4096) & 15;   obase = 4096; }
    else if (s < 8192) { src = it_w1; K = 192; NT = 8; r = (s-5120) / 24;   k8 = (s-5120) % 24;   obase = 5120; }
    else               { src = it_w2; K = 128; NT = 4; r = (s-8192) >> 4;   k8 = (s-8192) & 15;   obase = 8192; }
    const int k = k8 * 8;
    const float4 f0 = *(const float4*)&src[(size_t)r * K + k];
    const float4 f1 = *(const float4*)&src[(size_t)r * K + k + 4];
    const int ks = k >> 5, lg = (k >> 3) & 3;
    const int lp = lg * 16 + (r & 15), nt = r >> 4;
    const size_t slot = obase + (size_t)(ks * NT + nt) * 64 + lp;
    s8v wv;
    wv[0]=(short)f2bf(f0.x); wv[1]=(short)f2bf(f0.y); wv[2]=(short)f2bf(f0.z); wv[3]=(short)f2bf(f0.w);
    wv[4]=(short)f2bf(f1.x); wv[5]=(short)f2bf(f1.y); wv[6]=(short)f2bf(f1.z); wv[7]=(short)f2bf(f1.w);
    *(s8v*)&blob[slot * 8] = wv;
}

//======================================================================
// Kernel 1: history pooling from fp8 table (row = 64B). r9's version.
//======================================================================
__global__ __launch_bounds__(256)
void hist_pool_kernel(const int* __restrict__ history,
                      const float* __restrict__ ts_diff,
                      const uint2* __restrict__ emb8,
                      float* __restrict__ hist_out, int B)
{
    const int wave = threadIdx.x >> 6;
    const int lane = threadIdx.x & 63;
    const int b = blockIdx.x * 4 + wave;
    const int grp = lane >> 3;
    const int c8 = lane & 7;

    __shared__ float2 s_p[4][LP];

    const int*   hrow = history + (size_t)b * LL;
    const float* trow = ts_diff + (size_t)b * LL;

    float wpart = 0.f;
    #pragma unroll
    for (int l = lane; l < LP; l += 64) {
        int idx = 0; float w = 0.f;
        if (l < LL) {
            const int raw = hrow[l];
            if (raw > 0) { w = __expf(-LAMBDA * trow[l]); idx = raw; }
        }
        s_p[wave][l] = make_float2(w, __int_as_float(idx));
        wpart += w;
    }
    const float wsum = wave_reduce_sum(wpart);
    __syncthreads();

    float a[8];
    #pragma unroll
    for (int j = 0; j < 8; ++j) a[j] = 0.f;

    #pragma unroll 1
    for (int l0 = 0; l0 < LP; l0 += 128) {
        uint2 e[16]; float w[16];
        #pragma unroll
        for (int i = 0; i < 16; ++i) {
            const float2 p = s_p[wave][l0 + i * 8 + grp];
            w[i] = p.x;
            e[i] = emb8[(size_t)__float_as_int(p.y) * 8 + c8];
        }
        #pragma unroll
        for (int i = 0; i < 16; ++i) {
            const f2v d01 = __builtin_amdgcn_cvt_pk_f32_fp8((int)e[i].x, false);
            const f2v d23 = __builtin_amdgcn_cvt_pk_f32_fp8((int)e[i].x, true);
            const f2v d45 = __builtin_amdgcn_cvt_pk_f32_fp8((int)e[i].y, false);
            const f2v d67 = __builtin_amdgcn_cvt_pk_f32_fp8((int)e[i].y, true);
            a[0] = fmaf(w[i], d01[0], a[0]);
            a[1] = fmaf(w[i], d01[1], a[1]);
            a[2] = fmaf(w[i], d23[0], a[2]);
            a[3] = fmaf(w[i], d23[1], a[3]);
            a[4] = fmaf(w[i], d45[0], a[4]);
            a[5] = fmaf(w[i], d45[1], a[5]);
            a[6] = fmaf(w[i], d67[0], a[6]);
            a[7] = fmaf(w[i], d67[1], a[7]);
        }
    }
    #pragma unroll
    for (int off = 8; off <= 32; off <<= 1)
        #pragma unroll
        for (int j = 0; j < 8; ++j)
            a[j] += __shfl_xor(a[j], off, 64);

    if (grp == 0) {
        const float inv = 0.015625f / (wsum + 1e-8f);
        float4 o0 = make_float4(a[0]*inv, a[1]*inv, a[2]*inv, a[3]*inv);
        float4 o1 = make_float4(a[4]*inv, a[5]*inv, a[6]*inv, a[7]*inv);
        *(float4*)&hist_out[(size_t)b * DD + c8 * 8]     = o0;
        *(float4*)&hist_out[(size_t)b * DD + c8 * 8 + 4] = o1;
    }
}

//======================================================================
// X/H fragment slot: A-operand layout for mfma_f32_16x16x32_bf16
//======================================================================
#define PUT_FRAG(buf, NKS, r, d, val)                                   \
    do {                                                                \
        const int _mt = (r) >> 4, _ks = (d) >> 5;                       \
        const int _lp = (((d) >> 3) & 3) * 16 + ((r) & 15);             \
        (buf)[(((_mt) * (NKS) + _ks) * 64 + _lp) * 8 + ((d) & 7)] = f2bf(val); \
    } while (0)

//======================================================================
// Kernel 2: merged towers, M=16 rows/block, 16KB LDS -> ~4 blocks/CU.
// blocks [0,nU): user; [nU,2nU): item.
//======================================================================
__global__ __launch_bounds__(512)
void towers_kernel(
    const int* __restrict__ user_id, const int* __restrict__ top_genres,
    const int* __restrict__ item_id, const int* __restrict__ tmdb_genres,
    const float* __restrict__ hist_pool,
    const float* __restrict__ u_avg, const float* __restrict__ activity,
    const float* __restrict__ rel_year, const float* __restrict__ i_avg,
    const float* __restrict__ revenue,
    const float* __restrict__ emb_item, const float* __restrict__ emb_genre,
    const float* __restrict__ emb_user,
    const float* __restrict__ ut_cont_w, const float* __restrict__ ut_cont_b,
    const float* __restrict__ it_cont_w, const float* __restrict__ it_cont_b,
    const unsigned short* __restrict__ wblob,
    const float* __restrict__ ut_b1, const float* __restrict__ ut_g,
    const float* __restrict__ ut_be, const float* __restrict__ ut_b2,
    const float* __restrict__ it_b1, const float* __restrict__ it_g,
    const float* __restrict__ it_be, const float* __restrict__ it_b2,
    float* __restrict__ out, int B)
{
    const int tid = threadIdx.x, wave = tid >> 6, lane = tid & 63;
    const int nU = B / 16;
    const bool is_user = (int)blockIdx.x < nU;
    const int r0 = (is_user ? blockIdx.x : blockIdx.x - nU) * 16;

    __shared__ __align__(16) unsigned char  sXY[8 * 1024];  // sXf (bf16 frags) / sY (f32) alias
    __shared__ __align__(16) unsigned short sHf[4 * 64 * 8];// 4KB
    __shared__ __align__(16) float sO[16 * 64];             // 4KB

    unsigned short* sXf = (unsigned short*)sXY;
    float* sY = (float*)sXY;

    const f4v zero4 = {0.f, 0.f, 0.f, 0.f};

    if (is_user) {
        //---- features: wave handles rows wave*2, wave*2+1 ----
        #pragma unroll
        for (int i = 0; i < 2; ++i) {
            const int r = wave * 2 + i, b = r0 + r;
            const float ue = emb_user[(size_t)user_id[b] * DD + lane];
            const float hp = hist_pool[(size_t)b * DD + lane];
            const int* grow = top_genres + (size_t)b * GG;
            float gacc = 0.f, gw = 0.f;
            #pragma unroll
            for (int g = 0; g < GG; ++g) {
                const int idx = grow[g];
                const float m = (idx > 0) ? 1.f : 0.f;
                gacc = fmaf(m, emb_genre[idx * DD + lane], gacc);
                gw += m;
            }
            const float ug = gacc / (gw + 1e-8f);
            float uc = fmaf(u_avg[b], ut_cont_w[lane * 2 + 0],
                       fmaf(activity[b], ut_cont_w[lane * 2 + 1], ut_cont_b[lane]));
            uc = fmaxf(uc, 0.f);
            PUT_FRAG(sXf, 8, r, lane, ue);
            PUT_FRAG(sXf, 8, r, 64 + lane, hp);
            PUT_FRAG(sXf, 8, r, 128 + lane, ug);
            PUT_FRAG(sXf, 8, r, 192 + lane, uc);
        }
        __syncthreads();

        //---- L1 MFMA: M=16, N=128, K=256; wave = ntile ----
        f4v acc = zero4;
        #pragma unroll
        for (int ks = 0; ks < 8; ++ks) {
            const s8v av = *(const s8v*)&sXf[(ks * 64 + lane) * 8];
            const s8v bv = *(const s8v*)&wblob[((ks * 8 + wave) * 64 + lane) * 8];
            acc = __builtin_amdgcn_mfma_f32_16x16x32_bf16(av, bv, acc, 0, 0, 0);
        }
        __syncthreads();   // done reading sXf

        //---- y = acc + b1 -> sY [16][128] ----
        {
            const int n = wave * 16 + (lane & 15);
            const float bb = ut_b1[n];
            #pragma unroll
            for (int rg = 0; rg < 4; ++rg) {
                const int m = (lane >> 4) * 4 + rg;
                sY[m * 128 + n] = acc[rg] + bb;
            }
        }
        __syncthreads();

        //---- LN + ReLU -> sHf (separate buffer, no alias hazard) ----
        {
            const float g0 = ut_g[lane], g1 = ut_g[lane + 64];
            const float e0 = ut_be[lane], e1 = ut_be[lane + 64];
            #pragma unroll
            for (int i = 0; i < 2; ++i) {
                const int r = wave * 2 + i;
                const float a = sY[r * 128 + lane];
                const float c = sY[r * 128 + 64 + lane];
                const float mean = wave_reduce_sum(a + c) * (1.f / 128.f);
                const float da = a - mean, dc = c - mean;
                const float var = wave_reduce_sum(da * da + dc * dc) * (1.f / 128.f);
                const float rstd = rsqrtf(var + 1e-5f);
                const float h0 = fmaxf(fmaf(da * rstd, g0, e0), 0.f);
                const float h1 = fmaxf(fmaf(dc * rstd, g1, e1), 0.f);
                PUT_FRAG(sHf, 4, r, lane, h0);
                PUT_FRAG(sHf, 4, r, 64 + lane, h1);
            }
        }
        __syncthreads();

        //---- L2 MFMA: M=16, N=64, K=128; waves 0-3 ----
        if (wave < 4) {
            f4v acc2 = zero4;
            #pragma unroll
            for (int ks = 0; ks < 4; ++ks) {
                const s8v av = *(const s8v*)&sHf[(ks * 64 + lane) * 8];
                const s8v bv = *(const s8v*)&wblob[(4096 + (ks * 4 + wave) * 64 + lane) * 8];
                acc2 = __builtin_amdgcn_mfma_f32_16x16x32_bf16(av, bv, acc2, 0, 0, 0);
            }
            const int n = wave * 16 + (lane & 15);
            const float bb = ut_b2[n];
            #pragma unroll
            for (int rg = 0; rg < 4; ++rg) {
                const int m = (lane >> 4) * 4 + rg;
                sO[m * 64 + n] = acc2[rg] + bb;
            }
        }
        __syncthreads();

        //---- l2norm + store ----
        #pragma unroll
        for (int i = 0; i < 2; ++i) {
            const int r = wave * 2 + i;
            const float o = sO[r * 64 + lane];
            const float nrm = sqrtf(wave_reduce_sum(o * o));
            out[(size_t)(r0 + r) * DD + lane] = o / fmaxf(nrm, 1e-12f);
        }
    } else {
        //================= item tower, M=16 =================
        #pragma unroll
        for (int i = 0; i < 2; ++i) {
            const int r = wave * 2 + i, b = r0 + r;
            const float ie = emb_item[(size_t)item_id[b] * DD + lane];
            const int* grow = tmdb_genres + (size_t)b * GG;
            float gacc = 0.f, gw = 0.f;
            #pragma unroll
            for (int g = 0; g < GG; ++g) {
                const int idx = grow[g];
                const float m = (idx > 0) ? 1.f : 0.f;
                gacc = fmaf(m, emb_genre[idx * DD + lane], gacc);
                gw += m;
            }
            const float ig = gacc / (gw + 1e-8f);
            float ic = fmaf(rel_year[b], it_cont_w[lane * 3 + 0],
                       fmaf(i_avg[b],   it_cont_w[lane * 3 + 1],
                       fmaf(revenue[b], it_cont_w[lane * 3 + 2], it_cont_b[lane])));
            ic = fmaxf(ic, 0.f);
            PUT_FRAG(sXf, 6, r, lane, ie);
            PUT_FRAG(sXf, 6, r, 64 + lane, ig);
            PUT_FRAG(sXf, 6, r, 128 + lane, ic);
        }
        __syncthreads();

        //---- L1 MFMA: M=16, N=128, K=192 ----
        f4v acc = zero4;
        #pragma unroll
        for (int ks = 0; ks < 6; ++ks) {
            const s8v av = *(const s8v*)&sXf[(ks * 64 + lane) * 8];
            const s8v bv = *(const s8v*)&wblob[(5120 + (ks * 8 + wave) * 64 + lane) * 8];
            acc = __builtin_amdgcn_mfma_f32_16x16x32_bf16(av, bv, acc, 0, 0, 0);
        }
        __syncthreads();

        {
            const int n = wave * 16 + (lane & 15);
            const float bb = it_b1[n];
            #pragma unroll
            for (int rg = 0; rg < 4; ++rg) {
                const int m = (lane >> 4) * 4 + rg;
                sY[m * 128 + n] = acc[rg] + bb;
            }
        }
        __syncthreads();

        {
            const float g0 = it_g[lane], g1 = it_g[lane + 64];
            const float e0 = it_be[lane], e1 = it_be[lane + 64];
            #pragma unroll
            for (int i = 0; i < 2; ++i) {
                const int r = wave * 2 + i;
                const float a = sY[r * 128 + lane];
                const float c = sY[r * 128 + 64 + lane];
                const float mean = wave_reduce_sum(a + c) * (1.f / 128.f);
                const float da = a - mean, dc = c - mean;
                const float var = wave_reduce_sum(da * da + dc * dc) * (1.f / 128.f);
                const float rstd = rsqrtf(var + 1e-5f);
                const float h0 = fmaxf(fmaf(da * rstd, g0, e0), 0.f);
                const float h1 = fmaxf(fmaf(dc * rstd, g1, e1), 0.f);
                PUT_FRAG(sHf, 4, r, lane, h0);
                PUT_FRAG(sHf, 4, r, 64 + lane, h1);
            }
        }
        __syncthreads();

        if (wave < 4) {
            f4v acc2 = zero4;
            #pragma unroll
            for (int ks = 0; ks < 4; ++ks) {
                const s8v av = *(const s8v*)&sHf[(ks * 64 + lane) * 8];
                const s8v bv = *(const s8v*)&wblob[(8192 + (ks * 4 + wave) * 64 + lane) * 8];
                acc2 = __builtin_amdgcn_mfma_f32_16x16x32_bf16(av, bv, acc2, 0, 0, 0);
            }
            const int n = wave * 16 + (lane & 15);
            const float bb = it_b2[n];
            #pragma unroll
            for (int rg = 0; rg < 4; ++rg) {
                const int m = (lane >> 4) * 4 + rg;
                sO[m * 64 + n] = acc2[rg] + bb;
            }
        }
        __syncthreads();

        #pragma unroll
        for (int i = 0; i < 2; ++i) {
            const int r = wave * 2 + i;
            const float o = sO[r * 64 + lane];
            const float nrm = sqrtf(wave_reduce_sum(o * o));
            out[(size_t)B * DD + (size_t)(r0 + r) * DD + lane] = o / fmaxf(nrm, 1e-12f);
        }
    }
}

extern "C" void kernel_launch(void* const* d_in, const int* in_sizes, int n_in,
                              void* d_out, int out_size, void* d_ws, size_t ws_size,
                              hipStream_t stream) {
    const int*   user_id     = (const int*)  d_in[0];
    const int*   history     = (const int*)  d_in[1];
    const int*   top_genres  = (const int*)  d_in[2];
    const int*   item_id     = (const int*)  d_in[3];
    const int*   tmdb_genres = (const int*)  d_in[4];
    const float* ts_diff     = (const float*)d_in[5];
    const float* u_avg       = (const float*)d_in[6];
    const float* activity    = (const float*)d_in[7];
    const float* rel_year    = (const float*)d_in[8];
    const float* i_avg       = (const float*)d_in[9];
    const float* revenue     = (const float*)d_in[10];
    const float* emb_item    = (const float*)d_in[11];
    const float* emb_genre   = (const float*)d_in[12];
    const float* emb_user    = (const float*)d_in[13];
    const float* ut_cont_w   = (const float*)d_in[14];
    const float* ut_cont_b   = (const float*)d_in[15];
    const float* ut_w1       = (const float*)d_in[16];
    const float* ut_b1       = (const float*)d_in[17];
    const float* ut_g        = (const float*)d_in[18];
    const float* ut_be       = (const float*)d_in[19];
    const float* ut_w2       = (const float*)d_in[20];
    const float* ut_b2       = (const float*)d_in[21];
    const float* it_cont_w   = (const float*)d_in[22];
    const float* it_cont_b   = (const float*)d_in[23];
    const float* it_w1       = (const float*)d_in[24];
    const float* it_b1       = (const float*)d_in[25];
    const float* it_g        = (const float*)d_in[26];
    const float* it_be       = (const float*)d_in[27];
    const float* it_w2       = (const float*)d_in[28];
    const float* it_b2       = (const float*)d_in[29];

    const int B = in_sizes[0];                 // 16384
    const int n_item = in_sizes[11];           // V_ITEM * 64

    // workspace layout
    unsigned int* emb8 = (unsigned int*)d_ws;                         // 6.4MB
    size_t off = (size_t)(n_item / 4) * sizeof(unsigned int);
    off = (off + 255) & ~(size_t)255;
    unsigned short* wblob = (unsigned short*)((char*)d_ws + off);     // 144KB
    off += (size_t)9216 * 8 * sizeof(unsigned short);
    off = (off + 255) & ~(size_t)255;
    float* hist_pool = (float*)((char*)d_ws + off);                   // 4MB

    hipLaunchKernelGGL(prep_kernel, dim3(FP8_BLOCKS + 36), dim3(256), 0, stream,
        emb_item, ut_w1, ut_w2, it_w1, it_w2, emb8, wblob, n_item / 8);

    hipLaunchKernelGGL(hist_pool_kernel, dim3(B / 4), dim3(256), 0, stream,
        history, ts_diff, (const uint2*)emb8, hist_pool, B);

    hipLaunchKernelGGL(towers_kernel, dim3(2 * (B / 16)), dim3(512), 0, stream,
        user_id, top_genres, item_id, tmdb_genres, hist_pool,
        u_avg, activity, rel_year, i_avg, revenue,
        emb_item, emb_genre, emb_user,
        ut_cont_w, ut_cont_b, it_cont_w, it_cont_b,
        wblob, ut_b1, ut_g, ut_be, ut_b2, it_b1, it_g, it_be, it_b2,
        (float*)d_out, B);
}

// Round 14
// 53.499 us; speedup vs baseline: 1.8488x; 1.1709x over previous
//
#include <hip/hip_runtime.h>

#define DD 64
#define LL 200
#define LP 256     // LL padded
#define GG 6
#define LAMBDA 0.001f
#define PREP_BLOCKS 3126   // ceil(100001*8 / 256) uint-units (fp4) == ceil(.../8/256) (fp8)

#if __has_builtin(__builtin_amdgcn_cvt_scalef32_pk_f32_fp4) && __has_builtin(__builtin_amdgcn_cvt_scalef32_pk_fp4_f32)
#define USE_FP4 1
#else
#define USE_FP4 0
#endif

typedef __attribute__((ext_vector_type(8))) short s8v;   // 8 bf16 (4 VGPRs)
typedef __attribute__((ext_vector_type(4))) float f4v;   // MFMA accumulator
typedef __attribute__((ext_vector_type(2))) float f2v;

__device__ __forceinline__ float wave_reduce_sum(float v) {
    #pragma unroll
    for (int off = 32; off > 0; off >>= 1)
        v += __shfl_xor(v, off, 64);
    return v;
}

__device__ __forceinline__ unsigned short f2bf(float f) {
    union { float f; unsigned int u; } v; v.f = f;
    return (unsigned short)((v.u + 0x7FFFu + ((v.u >> 16) & 1u)) >> 16);  // RNE
}

//======================================================================
// Kernel 0: fused prep.
//  blocks [0, PREP_BLOCKS): emb_item fp32 -> fp4 (x64 scale) table
//                           (fallback: fp8 e4m3 table)
//  blocks [PREP_BLOCKS, +36): MLP weights -> frag-order bf16 blob
//======================================================================
__global__ __launch_bounds__(256)
void prep_kernel(const float* __restrict__ emb_item,
                 const float* __restrict__ ut_w1, const float* __restrict__ ut_w2,
                 const float* __restrict__ it_w1, const float* __restrict__ it_w2,
                 unsigned int* __restrict__ emb_tab,
                 unsigned short* __restrict__ blob, int V)
{
    if (blockIdx.x < PREP_BLOCKS) {
        const int i = blockIdx.x * 256 + threadIdx.x;   // uint-unit index
#if USE_FP4
        if (i < V * 8) {      // uint = 8 fp4 dims; row = 8 uints (32B)
            const int v = i >> 3, c = i & 7;
            const float4 f0 = *(const float4*)&emb_item[(size_t)v * 64 + c * 8];
            const float4 f1 = *(const float4*)&emb_item[(size_t)v * 64 + c * 8 + 4];
            unsigned int o = 0;
            o = __builtin_amdgcn_cvt_scalef32_pk_fp4_f32(o, f0.x * 64.f, f0.y * 64.f, 1.0f, 0);
            o = __builtin_amdgcn_cvt_scalef32_pk_fp4_f32(o, f0.z * 64.f, f0.w * 64.f, 1.0f, 1);
            o = __builtin_amdgcn_cvt_scalef32_pk_fp4_f32(o, f1.x * 64.f, f1.y * 64.f, 1.0f, 2);
            o = __builtin_amdgcn_cvt_scalef32_pk_fp4_f32(o, f1.z * 64.f, f1.w * 64.f, 1.0f, 3);
            emb_tab[i] = o;
        }
#else
        if (i < V * 8) {      // pair of uints = 8 fp8 dims; row = 16 uints (64B)
            const float4 f0 = *(const float4*)&emb_item[(size_t)i * 8];
            const float4 f1 = *(const float4*)&emb_item[(size_t)i * 8 + 4];
            int lo = __builtin_amdgcn_cvt_pk_fp8_f32(f0.x * 64.f, f0.y * 64.f, 0, false);
            lo     = __builtin_amdgcn_cvt_pk_fp8_f32(f0.z * 64.f, f0.w * 64.f, lo, true);
            int hi = __builtin_amdgcn_cvt_pk_fp8_f32(f1.x * 64.f, f1.y * 64.f, 0, false);
            hi     = __builtin_amdgcn_cvt_pk_fp8_f32(f1.z * 64.f, f1.w * 64.f, hi, true);
            uint2 o; o.x = (unsigned int)lo; o.y = (unsigned int)hi;
            *(uint2*)&emb_tab[(size_t)i * 2] = o;
        }
#endif
        return;
    }
    const int s = (blockIdx.x - PREP_BLOCKS) * 256 + threadIdx.x;   // 0..9215
    if (s >= 9216) return;
    const float* src; int K, NT, r, k8; size_t obase;
    if (s < 4096)      { src = ut_w1; K = 256; NT = 8; r = s >> 5;          k8 = s & 31;          obase = 0; }
    else if (s < 5120) { src = ut_w2; K = 128; NT = 4; r = (s-4096) >> 4;   k8 = (s-4096) & 15;   obase = 4096; }
    else if (s < 8192) { src = it_w1; K = 192; NT = 8; r = (s-5120) / 24;   k8 = (s-5120) % 24;   obase = 5120; }
    else               { src = it_w2; K = 128; NT = 4; r = (s-8192) >> 4;   k8 = (s-8192) & 15;   obase = 8192; }
    const int k = k8 * 8;
    const float4 f0 = *(const float4*)&src[(size_t)r * K + k];
    const float4 f1 = *(const float4*)&src[(size_t)r * K + k + 4];
    const int ks = k >> 5, lg = (k >> 3) & 3;
    const int lp = lg * 16 + (r & 15), nt = r >> 4;
    const size_t slot = obase + (size_t)(ks * NT + nt) * 64 + lp;
    s8v wv;
    wv[0]=(short)f2bf(f0.x); wv[1]=(short)f2bf(f0.y); wv[2]=(short)f2bf(f0.z); wv[3]=(short)f2bf(f0.w);
    wv[4]=(short)f2bf(f1.x); wv[5]=(short)f2bf(f1.y); wv[6]=(short)f2bf(f1.z); wv[7]=(short)f2bf(f1.w);
    *(s8v*)&blob[slot * 8] = wv;
}

//======================================================================
// Kernel 1: history pooling from fp4 table (row = 32B) or fp8 (64B).
// One wave per row; 8 entry-subgroups x 8 lanes.
//======================================================================
__global__ __launch_bounds__(256)
void hist_pool_kernel(const int* __restrict__ history,
                      const float* __restrict__ ts_diff,
                      const unsigned int* __restrict__ emb_tab,
                      float* __restrict__ hist_out, int B)
{
    const int wave = threadIdx.x >> 6;
    const int lane = threadIdx.x & 63;
    const int b = blockIdx.x * 4 + wave;
    const int grp = lane >> 3;
    const int c8 = lane & 7;

    __shared__ float2 s_p[4][LP];

    const int*   hrow = history + (size_t)b * LL;
    const float* trow = ts_diff + (size_t)b * LL;

    float wpart = 0.f;
    #pragma unroll
    for (int l = lane; l < LP; l += 64) {
        int idx = 0; float w = 0.f;
        if (l < LL) {
            const int raw = hrow[l];
            if (raw > 0) { w = __expf(-LAMBDA * trow[l]); idx = raw; }
        }
        s_p[wave][l] = make_float2(w, __int_as_float(idx));
        wpart += w;
    }
    const float wsum = wave_reduce_sum(wpart);
    __syncthreads();

    float a[8];
    #pragma unroll
    for (int j = 0; j < 8; ++j) a[j] = 0.f;

#if USE_FP4
    #pragma unroll 1
    for (int l0 = 0; l0 < LP; l0 += 128) {
        unsigned int e[16]; float w[16];
        #pragma unroll
        for (int i = 0; i < 16; ++i) {
            const float2 p = s_p[wave][l0 + i * 8 + grp];
            w[i] = p.x;
            e[i] = emb_tab[(size_t)__float_as_int(p.y) * 8 + c8];
        }
        #pragma unroll
        for (int i = 0; i < 16; ++i) {
            const f2v d01 = __builtin_amdgcn_cvt_scalef32_pk_f32_fp4(e[i], 1.0f, 0);
            const f2v d23 = __builtin_amdgcn_cvt_scalef32_pk_f32_fp4(e[i], 1.0f, 1);
            const f2v d45 = __builtin_amdgcn_cvt_scalef32_pk_f32_fp4(e[i], 1.0f, 2);
            const f2v d67 = __builtin_amdgcn_cvt_scalef32_pk_f32_fp4(e[i], 1.0f, 3);
            a[0] = fmaf(w[i], d01[0], a[0]);
            a[1] = fmaf(w[i], d01[1], a[1]);
            a[2] = fmaf(w[i], d23[0], a[2]);
            a[3] = fmaf(w[i], d23[1], a[3]);
            a[4] = fmaf(w[i], d45[0], a[4]);
            a[5] = fmaf(w[i], d45[1], a[5]);
            a[6] = fmaf(w[i], d67[0], a[6]);
            a[7] = fmaf(w[i], d67[1], a[7]);
        }
    }
#else
    #pragma unroll 1
    for (int l0 = 0; l0 < LP; l0 += 128) {
        uint2 e[16]; float w[16];
        #pragma unroll
        for (int i = 0; i < 16; ++i) {
            const float2 p = s_p[wave][l0 + i * 8 + grp];
            w[i] = p.x;
            e[i] = *(const uint2*)&emb_tab[(size_t)__float_as_int(p.y) * 16 + c8 * 2];
        }
        #pragma unroll
        for (int i = 0; i < 16; ++i) {
            const f2v d01 = __builtin_amdgcn_cvt_pk_f32_fp8((int)e[i].x, false);
            const f2v d23 = __builtin_amdgcn_cvt_pk_f32_fp8((int)e[i].x, true);
            const f2v d45 = __builtin_amdgcn_cvt_pk_f32_fp8((int)e[i].y, false);
            const f2v d67 = __builtin_amdgcn_cvt_pk_f32_fp8((int)e[i].y, true);
            a[0] = fmaf(w[i], d01[0], a[0]);
            a[1] = fmaf(w[i], d01[1], a[1]);
            a[2] = fmaf(w[i], d23[0], a[2]);
            a[3] = fmaf(w[i], d23[1], a[3]);
            a[4] = fmaf(w[i], d45[0], a[4]);
            a[5] = fmaf(w[i], d45[1], a[5]);
            a[6] = fmaf(w[i], d67[0], a[6]);
            a[7] = fmaf(w[i], d67[1], a[7]);
        }
    }
#endif
    #pragma unroll
    for (int off = 8; off <= 32; off <<= 1)
        #pragma unroll
        for (int j = 0; j < 8; ++j)
            a[j] += __shfl_xor(a[j], off, 64);

    if (grp == 0) {
        const float inv = 0.015625f / (wsum + 1e-8f);   // 1/64 descale folded in
        float4 o0 = make_float4(a[0]*inv, a[1]*inv, a[2]*inv, a[3]*inv);
        float4 o1 = make_float4(a[4]*inv, a[5]*inv, a[6]*inv, a[7]*inv);
        *(float4*)&hist_out[(size_t)b * DD + c8 * 8]     = o0;
        *(float4*)&hist_out[(size_t)b * DD + c8 * 8 + 4] = o1;
    }
}

//======================================================================
// X/H fragment slot: A-operand layout for mfma_f32_16x16x32_bf16
//======================================================================
#define PUT_FRAG(buf, NKS, r, d, val)                                   \
    do {                                                                \
        const int _mt = (r) >> 4, _ks = (d) >> 5;                       \
        const int _lp = (((d) >> 3) & 3) * 16 + ((r) & 15);             \
        (buf)[(((_mt) * (NKS) + _ks) * 64 + _lp) * 8 + ((d) & 7)] = f2bf(val); \
    } while (0)

//======================================================================
// Kernel 2: merged towers, M=16 rows/block, 16KB LDS (r13 verbatim).
//======================================================================
__global__ __launch_bounds__(512)
void towers_kernel(
    const int* __restrict__ user_id, const int* __restrict__ top_genres,
    const int* __restrict__ item_id, const int* __restrict__ tmdb_genres,
    const float* __restrict__ hist_pool,
    const float* __restrict__ u_avg, const float* __restrict__ activity,
    const float* __restrict__ rel_year, const float* __restrict__ i_avg,
    const float* __restrict__ revenue,
    const float* __restrict__ emb_item, const float* __restrict__ emb_genre,
    const float* __restrict__ emb_user,
    const float* __restrict__ ut_cont_w, const float* __restrict__ ut_cont_b,
    const float* __restrict__ it_cont_w, const float* __restrict__ it_cont_b,
    const unsigned short* __restrict__ wblob,
    const float* __restrict__ ut_b1, const float* __restrict__ ut_g,
    const float* __restrict__ ut_be, const float* __restrict__ ut_b2,
    const float* __restrict__ it_b1, const float* __restrict__ it_g,
    const float* __restrict__ it_be, const float* __restrict__ it_b2,
    float* __restrict__ out, int B)
{
    const int tid = threadIdx.x, wave = tid >> 6, lane = tid & 63;
    const int nU = B / 16;
    const bool is_user = (int)blockIdx.x < nU;
    const int r0 = (is_user ? blockIdx.x : blockIdx.x - nU) * 16;

    __shared__ __align__(16) unsigned char  sXY[8 * 1024];
    __shared__ __align__(16) unsigned short sHf[4 * 64 * 8];
    __shared__ __align__(16) float sO[16 * 64];

    unsigned short* sXf = (unsigned short*)sXY;
    float* sY = (float*)sXY;

    const f4v zero4 = {0.f, 0.f, 0.f, 0.f};

    if (is_user) {
        #pragma unroll
        for (int i = 0; i < 2; ++i) {
            const int r = wave * 2 + i, b = r0 + r;
            const float ue = emb_user[(size_t)user_id[b] * DD + lane];
            const float hp = hist_pool[(size_t)b * DD + lane];
            const int* grow = top_genres + (size_t)b * GG;
            float gacc = 0.f, gw = 0.f;
            #pragma unroll
            for (int g = 0; g < GG; ++g) {
                const int idx = grow[g];
                const float m = (idx > 0) ? 1.f : 0.f;
                gacc = fmaf(m, emb_genre[idx * DD + lane], gacc);
                gw += m;
            }
            const float ug = gacc / (gw + 1e-8f);
            float uc = fmaf(u_avg[b], ut_cont_w[lane * 2 + 0],
                       fmaf(activity[b], ut_cont_w[lane * 2 + 1], ut_cont_b[lane]));
            uc = fmaxf(uc, 0.f);
            PUT_FRAG(sXf, 8, r, lane, ue);
            PUT_FRAG(sXf, 8, r, 64 + lane, hp);
            PUT_FRAG(sXf, 8, r, 128 + lane, ug);
            PUT_FRAG(sXf, 8, r, 192 + lane, uc);
        }
        __syncthreads();

        f4v acc = zero4;
        #pragma unroll
        for (int ks = 0; ks < 8; ++ks) {
            const s8v av = *(const s8v*)&sXf[(ks * 64 + lane) * 8];
            const s8v bv = *(const s8v*)&wblob[((ks * 8 + wave) * 64 + lane) * 8];
            acc = __builtin_amdgcn_mfma_f32_16x16x32_bf16(av, bv, acc, 0, 0, 0);
        }
        __syncthreads();

        {
            const int n = wave * 16 + (lane & 15);
            const float bb = ut_b1[n];
            #pragma unroll
            for (int rg = 0; rg < 4; ++rg) {
                const int m = (lane >> 4) * 4 + rg;
                sY[m * 128 + n] = acc[rg] + bb;
            }
        }
        __syncthreads();

        {
            const float g0 = ut_g[lane], g1 = ut_g[lane + 64];
            const float e0 = ut_be[lane], e1 = ut_be[lane + 64];
            #pragma unroll
            for (int i = 0; i < 2; ++i) {
                const int r = wave * 2 + i;
                const float a = sY[r * 128 + lane];
                const float c = sY[r * 128 + 64 + lane];
                const float mean = wave_reduce_sum(a + c) * (1.f / 128.f);
                const float da = a - mean, dc = c - mean;
                const float var = wave_reduce_sum(da * da + dc * dc) * (1.f / 128.f);
                const float rstd = rsqrtf(var + 1e-5f);
                const float h0 = fmaxf(fmaf(da * rstd, g0, e0), 0.f);
                const float h1 = fmaxf(fmaf(dc * rstd, g1, e1), 0.f);
                PUT_FRAG(sHf, 4, r, lane, h0);
                PUT_FRAG(sHf, 4, r, 64 + lane, h1);
            }
        }
        __syncthreads();

        if (wave < 4) {
            f4v acc2 = zero4;
            #pragma unroll
            for (int ks = 0; ks < 4; ++ks) {
                const s8v av = *(const s8v*)&sHf[(ks * 64 + lane) * 8];
                const s8v bv = *(const s8v*)&wblob[(4096 + (ks * 4 + wave) * 64 + lane) * 8];
                acc2 = __builtin_amdgcn_mfma_f32_16x16x32_bf16(av, bv, acc2, 0, 0, 0);
            }
            const int n = wave * 16 + (lane & 15);
            const float bb = ut_b2[n];
            #pragma unroll
            for (int rg = 0; rg < 4; ++rg) {
                const int m = (lane >> 4) * 4 + rg;
                sO[m * 64 + n] = acc2[rg] + bb;
            }
        }
        __syncthreads();

        #pragma unroll
        for (int i = 0; i < 2; ++i) {
            const int r = wave * 2 + i;
            const float o = sO[r * 64 + lane];
            const float nrm = sqrtf(wave_reduce_sum(o * o));
            out[(size_t)(r0 + r) * DD + lane] = o / fmaxf(nrm, 1e-12f);
        }
    } else {
        #pragma unroll
        for (int i = 0; i < 2; ++i) {
            const int r = wave * 2 + i, b = r0 + r;
            const float ie = emb_item[(size_t)item_id[b] * DD + lane];
            const int* grow = tmdb_genres + (size_t)b * GG;
            float gacc = 0.f, gw = 0.f;
            #pragma unroll
            for (int g = 0; g < GG; ++g) {
                const int idx = grow[g];
                const float m = (idx > 0) ? 1.f : 0.f;
                gacc = fmaf(m, emb_genre[idx * DD + lane], gacc);
                gw += m;
            }
            const float ig = gacc / (gw + 1e-8f);
            float ic = fmaf(rel_year[b], it_cont_w[lane * 3 + 0],
                       fmaf(i_avg[b],   it_cont_w[lane * 3 + 1],
                       fmaf(revenue[b], it_cont_w[lane * 3 + 2], it_cont_b[lane])));
            ic = fmaxf(ic, 0.f);
            PUT_FRAG(sXf, 6, r, lane, ie);
            PUT_FRAG(sXf, 6, r, 64 + lane, ig);
            PUT_FRAG(sXf, 6, r, 128 + lane, ic);
        }
        __syncthreads();

        f4v acc = zero4;
        #pragma unroll
        for (int ks = 0; ks < 6; ++ks) {
            const s8v av = *(const s8v*)&sXf[(ks * 64 + lane) * 8];
            const s8v bv = *(const s8v*)&wblob[(5120 + (ks * 8 + wave) * 64 + lane) * 8];
            acc = __builtin_amdgcn_mfma_f32_16x16x32_bf16(av, bv, acc, 0, 0, 0);
        }
        __syncthreads();

        {
            const int n = wave * 16 + (lane & 15);
            const float bb = it_b1[n];
            #pragma unroll
            for (int rg = 0; rg < 4; ++rg) {
                const int m = (lane >> 4) * 4 + rg;
                sY[m * 128 + n] = acc[rg] + bb;
            }
        }
        __syncthreads();

        {
            const float g0 = it_g[lane], g1 = it_g[lane + 64];
            const float e0 = it_be[lane], e1 = it_be[lane + 64];
            #pragma unroll
            for (int i = 0; i < 2; ++i) {
                const int r = wave * 2 + i;
                const float a = sY[r * 128 + lane];
                const float c = sY[r * 128 + 64 + lane];
                const float mean = wave_reduce_sum(a + c) * (1.f / 128.f);
                const float da = a - mean, dc = c - mean;
                const float var = wave_reduce_sum(da * da + dc * dc) * (1.f / 128.f);
                const float rstd = rsqrtf(var + 1e-5f);
                const float h0 = fmaxf(fmaf(da * rstd, g0, e0), 0.f);
                const float h1 = fmaxf(fmaf(dc * rstd, g1, e1), 0.f);
                PUT_FRAG(sHf, 4, r, lane, h0);
                PUT_FRAG(sHf, 4, r, 64 + lane, h1);
            }
        }
        __syncthreads();

        if (wave < 4) {
            f4v acc2 = zero4;
            #pragma unroll
            for (int ks = 0; ks < 4; ++ks) {
                const s8v av = *(const s8v*)&sHf[(ks * 64 + lane) * 8];
                const s8v bv = *(const s8v*)&wblob[(8192 + (ks * 4 + wave) * 64 + lane) * 8];
                acc2 = __builtin_amdgcn_mfma_f32_16x16x32_bf16(av, bv, acc2, 0, 0, 0);
            }
            const int n = wave * 16 + (lane & 15);
            const float bb = it_b2[n];
            #pragma unroll
            for (int rg = 0; rg < 4; ++rg) {
                const int m = (lane >> 4) * 4 + rg;
                sO[m * 64 + n] = acc2[rg] + bb;
            }
        }
        __syncthreads();

        #pragma unroll
        for (int i = 0; i < 2; ++i) {
            const int r = wave * 2 + i;
            const float o = sO[r * 64 + lane];
            const float nrm = sqrtf(wave_reduce_sum(o * o));
            out[(size_t)B * DD + (size_t)(r0 + r) * DD + lane] = o / fmaxf(nrm, 1e-12f);
        }
    }
}

extern "C" void kernel_launch(void* const* d_in, const int* in_sizes, int n_in,
                              void* d_out, int out_size, void* d_ws, size_t ws_size,
                              hipStream_t stream) {
    const int*   user_id     = (const int*)  d_in[0];
    const int*   history     = (const int*)  d_in[1];
    const int*   top_genres  = (const int*)  d_in[2];
    const int*   item_id     = (const int*)  d_in[3];
    const int*   tmdb_genres = (const int*)  d_in[4];
    const float* ts_diff     = (const float*)d_in[5];
    const float* u_avg       = (const float*)d_in[6];
    const float* activity    = (const float*)d_in[7];
    const float* rel_year    = (const float*)d_in[8];
    const float* i_avg       = (const float*)d_in[9];
    const float* revenue     = (const float*)d_in[10];
    const float* emb_item    = (const float*)d_in[11];
    const float* emb_genre   = (const float*)d_in[12];
    const float* emb_user    = (const float*)d_in[13];
    const float* ut_cont_w   = (const float*)d_in[14];
    const float* ut_cont_b   = (const float*)d_in[15];
    const float* ut_w1       = (const float*)d_in[16];
    const float* ut_b1       = (const float*)d_in[17];
    const float* ut_g        = (const float*)d_in[18];
    const float* ut_be       = (const float*)d_in[19];
    const float* ut_w2       = (const float*)d_in[20];
    const float* ut_b2       = (const float*)d_in[21];
    const float* it_cont_w   = (const float*)d_in[22];
    const float* it_cont_b   = (const float*)d_in[23];
    const float* it_w1       = (const float*)d_in[24];
    const float* it_b1       = (const float*)d_in[25];
    const float* it_g        = (const float*)d_in[26];
    const float* it_be       = (const float*)d_in[27];
    const float* it_w2       = (const float*)d_in[28];
    const float* it_b2       = (const float*)d_in[29];

    const int B = in_sizes[0];                 // 16384
    const int n_item = in_sizes[11];           // V_ITEM * 64
    const int V = n_item / DD;                 // 100001

    // workspace layout (reserve fp8-size table regardless of path)
    unsigned int* emb_tab = (unsigned int*)d_ws;                      // <= 6.4MB
    size_t off = (size_t)(n_item / 4) * sizeof(unsigned int);
    off = (off + 255) & ~(size_t)255;
    unsigned short* wblob = (unsigned short*)((char*)d_ws + off);     // 144KB
    off += (size_t)9216 * 8 * sizeof(unsigned short);
    off = (off + 255) & ~(size_t)255;
    float* hist_pool = (float*)((char*)d_ws + off);                   // 4MB

    hipLaunchKernelGGL(prep_kernel, dim3(PREP_BLOCKS + 36), dim3(256), 0, stream,
        emb_item, ut_w1, ut_w2, it_w1, it_w2, emb_tab, wblob, V);

    hipLaunchKernelGGL(hist_pool_kernel, dim3(B / 4), dim3(256), 0, stream,
        history, ts_diff, emb_tab, hist_pool, B);

    hipLaunchKernelGGL(towers_kernel, dim3(2 * (B / 16)), dim3(512), 0, stream,
        user_id, top_genres, item_id, tmdb_genres, hist_pool,
        u_avg, activity, rel_year, i_avg, revenue,
        emb_item, emb_genre, emb_user,
        ut_cont_w, ut_cont_b, it_cont_w, it_cont_b,
        wblob, ut_b1, ut_g, ut_be, ut_b2, it_b1, it_g, it_be, it_b2,
        (float*)d_out, B);
}

// Round 15
// 51.489 us; speedup vs baseline: 1.9209x; 1.0390x over previous
//
#include <hip/hip_runtime.h>

#define DD 64
#define LL 200
#define GG 6
#define LAMBDA 0.001f
#define PREP_BLOCKS 3126   // ceil(100001*8 / 256) uint-units

#if __has_builtin(__builtin_amdgcn_cvt_scalef32_pk_f32_fp4) && __has_builtin(__builtin_amdgcn_cvt_scalef32_pk_fp4_f32)
#define USE_FP4 1
#else
#define USE_FP4 0
#endif

typedef __attribute__((ext_vector_type(8))) short s8v;   // 8 bf16 (4 VGPRs)
typedef __attribute__((ext_vector_type(4))) float f4v;   // MFMA accumulator
typedef __attribute__((ext_vector_type(2))) float f2v;

__device__ __forceinline__ float wave_reduce_sum(float v) {
    #pragma unroll
    for (int off = 32; off > 0; off >>= 1)
        v += __shfl_xor(v, off, 64);
    return v;
}

__device__ __forceinline__ unsigned short f2bf(float f) {
    union { float f; unsigned int u; } v; v.f = f;
    return (unsigned short)((v.u + 0x7FFFu + ((v.u >> 16) & 1u)) >> 16);  // RNE
}

//======================================================================
// Kernel 0: fused prep (fp4 table + frag-ordered bf16 weight blob).
//======================================================================
__global__ __launch_bounds__(256)
void prep_kernel(const float* __restrict__ emb_item,
                 const float* __restrict__ ut_w1, const float* __restrict__ ut_w2,
                 const float* __restrict__ it_w1, const float* __restrict__ it_w2,
                 unsigned int* __restrict__ emb_tab,
                 unsigned short* __restrict__ blob, int V)
{
    if (blockIdx.x < PREP_BLOCKS) {
        const int i = blockIdx.x * 256 + threadIdx.x;   // uint-unit index
#if USE_FP4
        if (i < V * 8) {      // uint = 8 fp4 dims; row = 8 uints (32B)
            const int v = i >> 3, c = i & 7;
            const float4 f0 = *(const float4*)&emb_item[(size_t)v * 64 + c * 8];
            const float4 f1 = *(const float4*)&emb_item[(size_t)v * 64 + c * 8 + 4];
            unsigned int o = 0;
            o = __builtin_amdgcn_cvt_scalef32_pk_fp4_f32(o, f0.x * 64.f, f0.y * 64.f, 1.0f, 0);
            o = __builtin_amdgcn_cvt_scalef32_pk_fp4_f32(o, f0.z * 64.f, f0.w * 64.f, 1.0f, 1);
            o = __builtin_amdgcn_cvt_scalef32_pk_fp4_f32(o, f1.x * 64.f, f1.y * 64.f, 1.0f, 2);
            o = __builtin_amdgcn_cvt_scalef32_pk_fp4_f32(o, f1.z * 64.f, f1.w * 64.f, 1.0f, 3);
            emb_tab[i] = o;
        }
#else
        if (i < V * 8) {      // pair of uints = 8 fp8 dims; row = 16 uints (64B)
            const float4 f0 = *(const float4*)&emb_item[(size_t)i * 8];
            const float4 f1 = *(const float4*)&emb_item[(size_t)i * 8 + 4];
            int lo = __builtin_amdgcn_cvt_pk_fp8_f32(f0.x * 64.f, f0.y * 64.f, 0, false);
            lo     = __builtin_amdgcn_cvt_pk_fp8_f32(f0.z * 64.f, f0.w * 64.f, lo, true);
            int hi = __builtin_amdgcn_cvt_pk_fp8_f32(f1.x * 64.f, f1.y * 64.f, 0, false);
            hi     = __builtin_amdgcn_cvt_pk_fp8_f32(f1.z * 64.f, f1.w * 64.f, hi, true);
            uint2 o; o.x = (unsigned int)lo; o.y = (unsigned int)hi;
            *(uint2*)&emb_tab[(size_t)i * 2] = o;
        }
#endif
        return;
    }
    const int s = (blockIdx.x - PREP_BLOCKS) * 256 + threadIdx.x;   // 0..9215
    if (s >= 9216) return;
    const float* src; int K, NT, r, k8; size_t obase;
    if (s < 4096)      { src = ut_w1; K = 256; NT = 8; r = s >> 5;          k8 = s & 31;          obase = 0; }
    else if (s < 5120) { src = ut_w2; K = 128; NT = 4; r = (s-4096) >> 4;   k8 = (s-4096) & 15;   obase = 4096; }
    else if (s < 8192) { src = it_w1; K = 192; NT = 8; r = (s-5120) / 24;   k8 = (s-5120) % 24;   obase = 5120; }
    else               { src = it_w2; K = 128; NT = 4; r = (s-8192) >> 4;   k8 = (s-8192) & 15;   obase = 8192; }
    const int k = k8 * 8;
    const float4 f0 = *(const float4*)&src[(size_t)r * K + k];
    const float4 f1 = *(const float4*)&src[(size_t)r * K + k + 4];
    const int ks = k >> 5, lg = (k >> 3) & 3;
    const int lp = lg * 16 + (r & 15), nt = r >> 4;
    const size_t slot = obase + (size_t)(ks * NT + nt) * 64 + lp;
    s8v wv;
    wv[0]=(short)f2bf(f0.x); wv[1]=(short)f2bf(f0.y); wv[2]=(short)f2bf(f0.z); wv[3]=(short)f2bf(f0.w);
    wv[4]=(short)f2bf(f1.x); wv[5]=(short)f2bf(f1.y); wv[6]=(short)f2bf(f1.z); wv[7]=(short)f2bf(f1.w);
    *(s8v*)&blob[slot * 8] = wv;
}

//======================================================================
// Kernel 1: history pooling, exact 200 entries (16-deep + 9-deep batches).
// One wave per row; 8 entry-subgroups x 8 lanes; fp4 row = 32B.
//======================================================================
__global__ __launch_bounds__(256)
void hist_pool_kernel(const int* __restrict__ history,
                      const float* __restrict__ ts_diff,
                      const unsigned int* __restrict__ emb_tab,
                      float* __restrict__ hist_out, int B)
{
    const int wave = threadIdx.x >> 6;
    const int lane = threadIdx.x & 63;
    const int b = blockIdx.x * 4 + wave;
    const int grp = lane >> 3;
    const int c8 = lane & 7;

    __shared__ float2 s_p[4][LL];

    const int*   hrow = history + (size_t)b * LL;
    const float* trow = ts_diff + (size_t)b * LL;

    float wpart = 0.f;
    #pragma unroll
    for (int l = lane; l < LL; l += 64) {
        int idx = 0; float w = 0.f;
        const int raw = hrow[l];
        if (raw > 0) { w = __expf(-LAMBDA * trow[l]); idx = raw; }
        s_p[wave][l] = make_float2(w, __int_as_float(idx));
        wpart += w;
    }
    const float wsum = wave_reduce_sum(wpart);
    __syncthreads();

    float a[8];
    #pragma unroll
    for (int j = 0; j < 8; ++j) a[j] = 0.f;

#if USE_FP4
    #define GATHER_DECODE(EW, N, BASE)                                           \
        do {                                                                     \
            unsigned int e_[N]; float w_[N];                                     \
            _Pragma("unroll")                                                    \
            for (int i = 0; i < N; ++i) {                                        \
                const float2 p = s_p[wave][(BASE) + i * 8 + grp];                \
                w_[i] = p.x;                                                     \
                e_[i] = emb_tab[(size_t)__float_as_int(p.y) * 8 + c8];           \
            }                                                                    \
            _Pragma("unroll")                                                    \
            for (int i = 0; i < N; ++i) {                                        \
                const f2v d01 = __builtin_amdgcn_cvt_scalef32_pk_f32_fp4(e_[i], 1.0f, 0); \
                const f2v d23 = __builtin_amdgcn_cvt_scalef32_pk_f32_fp4(e_[i], 1.0f, 1); \
                const f2v d45 = __builtin_amdgcn_cvt_scalef32_pk_f32_fp4(e_[i], 1.0f, 2); \
                const f2v d67 = __builtin_amdgcn_cvt_scalef32_pk_f32_fp4(e_[i], 1.0f, 3); \
                a[0] = fmaf(w_[i], d01[0], a[0]);                                \
                a[1] = fmaf(w_[i], d01[1], a[1]);                                \
                a[2] = fmaf(w_[i], d23[0], a[2]);                                \
                a[3] = fmaf(w_[i], d23[1], a[3]);                                \
                a[4] = fmaf(w_[i], d45[0], a[4]);                                \
                a[5] = fmaf(w_[i], d45[1], a[5]);                                \
                a[6] = fmaf(w_[i], d67[0], a[6]);                                \
                a[7] = fmaf(w_[i], d67[1], a[7]);                                \
            }                                                                    \
        } while (0)
#else
    #define GATHER_DECODE(EW, N, BASE)                                           \
        do {                                                                     \
            uint2 e_[N]; float w_[N];                                            \
            _Pragma("unroll")                                                    \
            for (int i = 0; i < N; ++i) {                                        \
                const float2 p = s_p[wave][(BASE) + i * 8 + grp];                \
                w_[i] = p.x;                                                     \
                e_[i] = *(const uint2*)&emb_tab[(size_t)__float_as_int(p.y) * 16 + c8 * 2]; \
            }                                                                    \
            _Pragma("unroll")                                                    \
            for (int i = 0; i < N; ++i) {                                        \
                const f2v d01 = __builtin_amdgcn_cvt_pk_f32_fp8((int)e_[i].x, false); \
                const f2v d23 = __builtin_amdgcn_cvt_pk_f32_fp8((int)e_[i].x, true);  \
                const f2v d45 = __builtin_amdgcn_cvt_pk_f32_fp8((int)e_[i].y, false); \
                const f2v d67 = __builtin_amdgcn_cvt_pk_f32_fp8((int)e_[i].y, true);  \
                a[0] = fmaf(w_[i], d01[0], a[0]);                                \
                a[1] = fmaf(w_[i], d01[1], a[1]);                                \
                a[2] = fmaf(w_[i], d23[0], a[2]);                                \
                a[3] = fmaf(w_[i], d23[1], a[3]);                                \
                a[4] = fmaf(w_[i], d45[0], a[4]);                                \
                a[5] = fmaf(w_[i], d45[1], a[5]);                                \
                a[6] = fmaf(w_[i], d67[0], a[6]);                                \
                a[7] = fmaf(w_[i], d67[1], a[7]);                                \
            }                                                                    \
        } while (0)
#endif

    GATHER_DECODE(unsigned int, 16, 0);    // entries   0..127
    GATHER_DECODE(unsigned int, 9, 128);   // entries 128..199

    #pragma unroll
    for (int off = 8; off <= 32; off <<= 1)
        #pragma unroll
        for (int j = 0; j < 8; ++j)
            a[j] += __shfl_xor(a[j], off, 64);

    if (grp == 0) {
        const float inv = 0.015625f / (wsum + 1e-8f);   // 1/64 descale folded in
        float4 o0 = make_float4(a[0]*inv, a[1]*inv, a[2]*inv, a[3]*inv);
        float4 o1 = make_float4(a[4]*inv, a[5]*inv, a[6]*inv, a[7]*inv);
        *(float4*)&hist_out[(size_t)b * DD + c8 * 8]     = o0;
        *(float4*)&hist_out[(size_t)b * DD + c8 * 8 + 4] = o1;
    }
}

//======================================================================
// X/H fragment slot: A-operand layout for mfma_f32_16x16x32_bf16
//======================================================================
#define PUT_FRAG(buf, NKS, r, d, val)                                   \
    do {                                                                \
        const int _mt = (r) >> 4, _ks = (d) >> 5;                       \
        const int _lp = (((d) >> 3) & 3) * 16 + ((r) & 15);             \
        (buf)[(((_mt) * (NKS) + _ks) * 64 + _lp) * 8 + ((d) & 7)] = f2bf(val); \
    } while (0)

//======================================================================
// Kernel 2: merged towers, M=16 rows/block, 16KB LDS (r13 verbatim).
//======================================================================
__global__ __launch_bounds__(512)
void towers_kernel(
    const int* __restrict__ user_id, const int* __restrict__ top_genres,
    const int* __restrict__ item_id, const int* __restrict__ tmdb_genres,
    const float* __restrict__ hist_pool,
    const float* __restrict__ u_avg, const float* __restrict__ activity,
    const float* __restrict__ rel_year, const float* __restrict__ i_avg,
    const float* __restrict__ revenue,
    const float* __restrict__ emb_item, const float* __restrict__ emb_genre,
    const float* __restrict__ emb_user,
    const float* __restrict__ ut_cont_w, const float* __restrict__ ut_cont_b,
    const float* __restrict__ it_cont_w, const float* __restrict__ it_cont_b,
    const unsigned short* __restrict__ wblob,
    const float* __restrict__ ut_b1, const float* __restrict__ ut_g,
    const float* __restrict__ ut_be, const float* __restrict__ ut_b2,
    const float* __restrict__ it_b1, const float* __restrict__ it_g,
    const float* __restrict__ it_be, const float* __restrict__ it_b2,
    float* __restrict__ out, int B)
{
    const int tid = threadIdx.x, wave = tid >> 6, lane = tid & 63;
    const int nU = B / 16;
    const bool is_user = (int)blockIdx.x < nU;
    const int r0 = (is_user ? blockIdx.x : blockIdx.x - nU) * 16;

    __shared__ __align__(16) unsigned char  sXY[8 * 1024];
    __shared__ __align__(16) unsigned short sHf[4 * 64 * 8];
    __shared__ __align__(16) float sO[16 * 64];

    unsigned short* sXf = (unsigned short*)sXY;
    float* sY = (float*)sXY;

    const f4v zero4 = {0.f, 0.f, 0.f, 0.f};

    if (is_user) {
        #pragma unroll
        for (int i = 0; i < 2; ++i) {
            const int r = wave * 2 + i, b = r0 + r;
            const float ue = emb_user[(size_t)user_id[b] * DD + lane];
            const float hp = hist_pool[(size_t)b * DD + lane];
            const int* grow = top_genres + (size_t)b * GG;
            float gacc = 0.f, gw = 0.f;
            #pragma unroll
            for (int g = 0; g < GG; ++g) {
                const int idx = grow[g];
                const float m = (idx > 0) ? 1.f : 0.f;
                gacc = fmaf(m, emb_genre[idx * DD + lane], gacc);
                gw += m;
            }
            const float ug = gacc / (gw + 1e-8f);
            float uc = fmaf(u_avg[b], ut_cont_w[lane * 2 + 0],
                       fmaf(activity[b], ut_cont_w[lane * 2 + 1], ut_cont_b[lane]));
            uc = fmaxf(uc, 0.f);
            PUT_FRAG(sXf, 8, r, lane, ue);
            PUT_FRAG(sXf, 8, r, 64 + lane, hp);
            PUT_FRAG(sXf, 8, r, 128 + lane, ug);
            PUT_FRAG(sXf, 8, r, 192 + lane, uc);
        }
        __syncthreads();

        f4v acc = zero4;
        #pragma unroll
        for (int ks = 0; ks < 8; ++ks) {
            const s8v av = *(const s8v*)&sXf[(ks * 64 + lane) * 8];
            const s8v bv = *(const s8v*)&wblob[((ks * 8 + wave) * 64 + lane) * 8];
            acc = __builtin_amdgcn_mfma_f32_16x16x32_bf16(av, bv, acc, 0, 0, 0);
        }
        __syncthreads();

        {
            const int n = wave * 16 + (lane & 15);
            const float bb = ut_b1[n];
            #pragma unroll
            for (int rg = 0; rg < 4; ++rg) {
                const int m = (lane >> 4) * 4 + rg;
                sY[m * 128 + n] = acc[rg] + bb;
            }
        }
        __syncthreads();

        {
            const float g0 = ut_g[lane], g1 = ut_g[lane + 64];
            const float e0 = ut_be[lane], e1 = ut_be[lane + 64];
            #pragma unroll
            for (int i = 0; i < 2; ++i) {
                const int r = wave * 2 + i;
                const float a = sY[r * 128 + lane];
                const float c = sY[r * 128 + 64 + lane];
                const float mean = wave_reduce_sum(a + c) * (1.f / 128.f);
                const float da = a - mean, dc = c - mean;
                const float var = wave_reduce_sum(da * da + dc * dc) * (1.f / 128.f);
                const float rstd = rsqrtf(var + 1e-5f);
                const float h0 = fmaxf(fmaf(da * rstd, g0, e0), 0.f);
                const float h1 = fmaxf(fmaf(dc * rstd, g1, e1), 0.f);
                PUT_FRAG(sHf, 4, r, lane, h0);
                PUT_FRAG(sHf, 4, r, 64 + lane, h1);
            }
        }
        __syncthreads();

        if (wave < 4) {
            f4v acc2 = zero4;
            #pragma unroll
            for (int ks = 0; ks < 4; ++ks) {
                const s8v av = *(const s8v*)&sHf[(ks * 64 + lane) * 8];
                const s8v bv = *(const s8v*)&wblob[(4096 + (ks * 4 + wave) * 64 + lane) * 8];
                acc2 = __builtin_amdgcn_mfma_f32_16x16x32_bf16(av, bv, acc2, 0, 0, 0);
            }
            const int n = wave * 16 + (lane & 15);
            const float bb = ut_b2[n];
            #pragma unroll
            for (int rg = 0; rg < 4; ++rg) {
                const int m = (lane >> 4) * 4 + rg;
                sO[m * 64 + n] = acc2[rg] + bb;
            }
        }
        __syncthreads();

        #pragma unroll
        for (int i = 0; i < 2; ++i) {
            const int r = wave * 2 + i;
            const float o = sO[r * 64 + lane];
            const float nrm = sqrtf(wave_reduce_sum(o * o));
            out[(size_t)(r0 + r) * DD + lane] = o / fmaxf(nrm, 1e-12f);
        }
    } else {
        #pragma unroll
        for (int i = 0; i < 2; ++i) {
            const int r = wave * 2 + i, b = r0 + r;
            const float ie = emb_item[(size_t)item_id[b] * DD + lane];
            const int* grow = tmdb_genres + (size_t)b * GG;
            float gacc = 0.f, gw = 0.f;
            #pragma unroll
            for (int g = 0; g < GG; ++g) {
                const int idx = grow[g];
                const float m = (idx > 0) ? 1.f : 0.f;
                gacc = fmaf(m, emb_genre[idx * DD + lane], gacc);
                gw += m;
            }
            const float ig = gacc / (gw + 1e-8f);
            float ic = fmaf(rel_year[b], it_cont_w[lane * 3 + 0],
                       fmaf(i_avg[b],   it_cont_w[lane * 3 + 1],
                       fmaf(revenue[b], it_cont_w[lane * 3 + 2], it_cont_b[lane])));
            ic = fmaxf(ic, 0.f);
            PUT_FRAG(sXf, 6, r, lane, ie);
            PUT_FRAG(sXf, 6, r, 64 + lane, ig);
            PUT_FRAG(sXf, 6, r, 128 + lane, ic);
        }
        __syncthreads();

        f4v acc = zero4;
        #pragma unroll
        for (int ks = 0; ks < 6; ++ks) {
            const s8v av = *(const s8v*)&sXf[(ks * 64 + lane) * 8];
            const s8v bv = *(const s8v*)&wblob[(5120 + (ks * 8 + wave) * 64 + lane) * 8];
            acc = __builtin_amdgcn_mfma_f32_16x16x32_bf16(av, bv, acc, 0, 0, 0);
        }
        __syncthreads();

        {
            const int n = wave * 16 + (lane & 15);
            const float bb = it_b1[n];
            #pragma unroll
            for (int rg = 0; rg < 4; ++rg) {
                const int m = (lane >> 4) * 4 + rg;
                sY[m * 128 + n] = acc[rg] + bb;
            }
        }
        __syncthreads();

        {
            const float g0 = it_g[lane], g1 = it_g[lane + 64];
            const float e0 = it_be[lane], e1 = it_be[lane + 64];
            #pragma unroll
            for (int i = 0; i < 2; ++i) {
                const int r = wave * 2 + i;
                const float a = sY[r * 128 + lane];
                const float c = sY[r * 128 + 64 + lane];
                const float mean = wave_reduce_sum(a + c) * (1.f / 128.f);
                const float da = a - mean, dc = c - mean;
                const float var = wave_reduce_sum(da * da + dc * dc) * (1.f / 128.f);
                const float rstd = rsqrtf(var + 1e-5f);
                const float h0 = fmaxf(fmaf(da * rstd, g0, e0), 0.f);
                const float h1 = fmaxf(fmaf(dc * rstd, g1, e1), 0.f);
                PUT_FRAG(sHf, 4, r, lane, h0);
                PUT_FRAG(sHf, 4, r, 64 + lane, h1);
            }
        }
        __syncthreads();

        if (wave < 4) {
            f4v acc2 = zero4;
            #pragma unroll
            for (int ks = 0; ks < 4; ++ks) {
                const s8v av = *(const s8v*)&sHf[(ks * 64 + lane) * 8];
                const s8v bv = *(const s8v*)&wblob[(8192 + (ks * 4 + wave) * 64 + lane) * 8];
                acc2 = __builtin_amdgcn_mfma_f32_16x16x32_bf16(av, bv, acc2, 0, 0, 0);
            }
            const int n = wave * 16 + (lane & 15);
            const float bb = it_b2[n];
            #pragma unroll
            for (int rg = 0; rg < 4; ++rg) {
                const int m = (lane >> 4) * 4 + rg;
                sO[m * 64 + n] = acc2[rg] + bb;
            }
        }
        __syncthreads();

        #pragma unroll
        for (int i = 0; i < 2; ++i) {
            const int r = wave * 2 + i;
            const float o = sO[r * 64 + lane];
            const float nrm = sqrtf(wave_reduce_sum(o * o));
            out[(size_t)B * DD + (size_t)(r0 + r) * DD + lane] = o / fmaxf(nrm, 1e-12f);
        }
    }
}

extern "C" void kernel_launch(void* const* d_in, const int* in_sizes, int n_in,
                              void* d_out, int out_size, void* d_ws, size_t ws_size,
                              hipStream_t stream) {
    const int*   user_id     = (const int*)  d_in[0];
    const int*   history     = (const int*)  d_in[1];
    const int*   top_genres  = (const int*)  d_in[2];
    const int*   item_id     = (const int*)  d_in[3];
    const int*   tmdb_genres = (const int*)  d_in[4];
    const float* ts_diff     = (const float*)d_in[5];
    const float* u_avg       = (const float*)d_in[6];
    const float* activity    = (const float*)d_in[7];
    const float* rel_year    = (const float*)d_in[8];
    const float* i_avg       = (const float*)d_in[9];
    const float* revenue     = (const float*)d_in[10];
    const float* emb_item    = (const float*)d_in[11];
    const float* emb_genre   = (const float*)d_in[12];
    const float* emb_user    = (const float*)d_in[13];
    const float* ut_cont_w   = (const float*)d_in[14];
    const float* ut_cont_b   = (const float*)d_in[15];
    const float* ut_w1       = (const float*)d_in[16];
    const float* ut_b1       = (const float*)d_in[17];
    const float* ut_g        = (const float*)d_in[18];
    const float* ut_be       = (const float*)d_in[19];
    const float* ut_w2       = (const float*)d_in[20];
    const float* ut_b2       = (const float*)d_in[21];
    const float* it_cont_w   = (const float*)d_in[22];
    const float* it_cont_b   = (const float*)d_in[23];
    const float* it_w1       = (const float*)d_in[24];
    const float* it_b1       = (const float*)d_in[25];
    const float* it_g        = (const float*)d_in[26];
    const float* it_be       = (const float*)d_in[27];
    const float* it_w2       = (const float*)d_in[28];
    const float* it_b2       = (const float*)d_in[29];

    const int B = in_sizes[0];                 // 16384
    const int n_item = in_sizes[11];           // V_ITEM * 64
    const int V = n_item / DD;                 // 100001

    // workspace layout (reserve fp8-size table regardless of path)
    unsigned int* emb_tab = (unsigned int*)d_ws;                      // <= 6.4MB
    size_t off = (size_t)(n_item / 4) * sizeof(unsigned int);
    off = (off + 255) & ~(size_t)255;
    unsigned short* wblob = (unsigned short*)((char*)d_ws + off);     // 144KB
    off += (size_t)9216 * 8 * sizeof(unsigned short);
    off = (off + 255) & ~(size_t)255;
    float* hist_pool = (float*)((char*)d_ws + off);                   // 4MB

    hipLaunchKernelGGL(prep_kernel, dim3(PREP_BLOCKS + 36), dim3(256), 0, stream,
        emb_item, ut_w1, ut_w2, it_w1, it_w2, emb_tab, wblob, V);

    hipLaunchKernelGGL(hist_pool_kernel, dim3(B / 4), dim3(256), 0, stream,
        history, ts_diff, emb_tab, hist_pool, B);

    hipLaunchKernelGGL(towers_kernel, dim3(2 * (B / 16)), dim3(512), 0, stream,
        user_id, top_genres, item_id, tmdb_genres, hist_pool,
        u_avg, activity, rel_year, i_avg, revenue,
        emb_item, emb_genre, emb_user,
        ut_cont_w, ut_cont_b, it_cont_w, it_cont_b,
        wblob, ut_b1, ut_g, ut_be, ut_b2, it_b1, it_g, it_be, it_b2,
        (float*)d_out, B);
}

// Round 16
// 50.878 us; speedup vs baseline: 1.9440x; 1.0120x over previous
//
#include <hip/hip_runtime.h>

#define DD 64
#define LL 200
#define GG 6
#define LAMBDA 0.001f
#define PREP_BLOCKS 3126   // ceil(100001*8 / 256) uint-units

#if __has_builtin(__builtin_amdgcn_cvt_scalef32_pk_f32_fp4) && __has_builtin(__builtin_amdgcn_cvt_scalef32_pk_fp4_f32)
#define USE_FP4 1
#else
#define USE_FP4 0
#endif

typedef __attribute__((ext_vector_type(8))) short s8v;   // 8 bf16 (4 VGPRs)
typedef __attribute__((ext_vector_type(4))) float f4v;   // MFMA accumulator
typedef __attribute__((ext_vector_type(2))) float f2v;

__device__ __forceinline__ float wave_reduce_sum(float v) {
    #pragma unroll
    for (int off = 32; off > 0; off >>= 1)
        v += __shfl_xor(v, off, 64);
    return v;
}

__device__ __forceinline__ unsigned short f2bf(float f) {
    union { float f; unsigned int u; } v; v.f = f;
    return (unsigned short)((v.u + 0x7FFFu + ((v.u >> 16) & 1u)) >> 16);  // RNE
}

//======================================================================
// Kernel 0: fused prep (fp4 table + frag-ordered bf16 weight blob).
//======================================================================
__global__ __launch_bounds__(256)
void prep_kernel(const float* __restrict__ emb_item,
                 const float* __restrict__ ut_w1, const float* __restrict__ ut_w2,
                 const float* __restrict__ it_w1, const float* __restrict__ it_w2,
                 unsigned int* __restrict__ emb_tab,
                 unsigned short* __restrict__ blob, int V)
{
    if (blockIdx.x < PREP_BLOCKS) {
        const int i = blockIdx.x * 256 + threadIdx.x;   // uint-unit index
#if USE_FP4
        if (i < V * 8) {      // uint = 8 fp4 dims; row = 8 uints (32B)
            const int v = i >> 3, c = i & 7;
            const float4 f0 = *(const float4*)&emb_item[(size_t)v * 64 + c * 8];
            const float4 f1 = *(const float4*)&emb_item[(size_t)v * 64 + c * 8 + 4];
            unsigned int o = 0;
            o = __builtin_amdgcn_cvt_scalef32_pk_fp4_f32(o, f0.x * 64.f, f0.y * 64.f, 1.0f, 0);
            o = __builtin_amdgcn_cvt_scalef32_pk_fp4_f32(o, f0.z * 64.f, f0.w * 64.f, 1.0f, 1);
            o = __builtin_amdgcn_cvt_scalef32_pk_fp4_f32(o, f1.x * 64.f, f1.y * 64.f, 1.0f, 2);
            o = __builtin_amdgcn_cvt_scalef32_pk_fp4_f32(o, f1.z * 64.f, f1.w * 64.f, 1.0f, 3);
            emb_tab[i] = o;
        }
#else
        if (i < V * 8) {      // pair of uints = 8 fp8 dims; row = 16 uints (64B)
            const float4 f0 = *(const float4*)&emb_item[(size_t)i * 8];
            const float4 f1 = *(const float4*)&emb_item[(size_t)i * 8 + 4];
            int lo = __builtin_amdgcn_cvt_pk_fp8_f32(f0.x * 64.f, f0.y * 64.f, 0, false);
            lo     = __builtin_amdgcn_cvt_pk_fp8_f32(f0.z * 64.f, f0.w * 64.f, lo, true);
            int hi = __builtin_amdgcn_cvt_pk_fp8_f32(f1.x * 64.f, f1.y * 64.f, 0, false);
            hi     = __builtin_amdgcn_cvt_pk_fp8_f32(f1.z * 64.f, f1.w * 64.f, hi, true);
            uint2 o; o.x = (unsigned int)lo; o.y = (unsigned int)hi;
            *(uint2*)&emb_tab[(size_t)i * 2] = o;
        }
#endif
        return;
    }
    const int s = (blockIdx.x - PREP_BLOCKS) * 256 + threadIdx.x;   // 0..9215
    if (s >= 9216) return;
    const float* src; int K, NT, r, k8; size_t obase;
    if (s < 4096)      { src = ut_w1; K = 256; NT = 8; r = s >> 5;          k8 = s & 31;          obase = 0; }
    else if (s < 5120) { src = ut_w2; K = 128; NT = 4; r = (s-4096) >> 4;   k8 = (s-4096) & 15;   obase = 4096; }
    else if (s < 8192) { src = it_w1; K = 192; NT = 8; r = (s-5120) / 24;   k8 = (s-5120) % 24;   obase = 5120; }
    else               { src = it_w2; K = 128; NT = 4; r = (s-8192) >> 4;   k8 = (s-8192) & 15;   obase = 8192; }
    const int k = k8 * 8;
    const float4 f0 = *(const float4*)&src[(size_t)r * K + k];
    const float4 f1 = *(const float4*)&src[(size_t)r * K + k + 4];
    const int ks = k >> 5, lg = (k >> 3) & 3;
    const int lp = lg * 16 + (r & 15), nt = r >> 4;
    const size_t slot = obase + (size_t)(ks * NT + nt) * 64 + lp;
    s8v wv;
    wv[0]=(short)f2bf(f0.x); wv[1]=(short)f2bf(f0.y); wv[2]=(short)f2bf(f0.z); wv[3]=(short)f2bf(f0.w);
    wv[4]=(short)f2bf(f1.x); wv[5]=(short)f2bf(f1.y); wv[6]=(short)f2bf(f1.z); wv[7]=(short)f2bf(f1.w);
    *(s8v*)&blob[slot * 8] = wv;
}

//======================================================================
// Kernel 1: history pooling, exact 200 entries (16-deep + 9-deep).
// One wave per row; 8 entry-subgroups x 8 lanes; fp4 row = 32B.
//======================================================================
__global__ __launch_bounds__(256)
void hist_pool_kernel(const int* __restrict__ history,
                      const float* __restrict__ ts_diff,
                      const unsigned int* __restrict__ emb_tab,
                      float* __restrict__ hist_out, int B)
{
    const int wave = threadIdx.x >> 6;
    const int lane = threadIdx.x & 63;
    const int b = blockIdx.x * 4 + wave;
    const int grp = lane >> 3;
    const int c8 = lane & 7;

    __shared__ float2 s_p[4][LL];

    const int*   hrow = history + (size_t)b * LL;
    const float* trow = ts_diff + (size_t)b * LL;

    float wpart = 0.f;
    #pragma unroll
    for (int l = lane; l < LL; l += 64) {
        int idx = 0; float w = 0.f;
        const int raw = hrow[l];
        if (raw > 0) { w = __expf(-LAMBDA * trow[l]); idx = raw; }
        s_p[wave][l] = make_float2(w, __int_as_float(idx));
        wpart += w;
    }
    const float wsum = wave_reduce_sum(wpart);
    // no __syncthreads: s_p slice is wave-private, LDS ops within a wave
    // are ordered by lgkmcnt.

    float a[8];
    #pragma unroll
    for (int j = 0; j < 8; ++j) a[j] = 0.f;

#if USE_FP4
    #define GATHER_DECODE(N, BASE)                                               \
        do {                                                                     \
            unsigned int e_[N]; float w_[N];                                     \
            _Pragma("unroll")                                                    \
            for (int i = 0; i < N; ++i) {                                        \
                const float2 p = s_p[wave][(BASE) + i * 8 + grp];                \
                w_[i] = p.x;                                                     \
                e_[i] = emb_tab[(size_t)__float_as_int(p.y) * 8 + c8];           \
            }                                                                    \
            _Pragma("unroll")                                                    \
            for (int i = 0; i < N; ++i) {                                        \
                const f2v d01 = __builtin_amdgcn_cvt_scalef32_pk_f32_fp4(e_[i], 1.0f, 0); \
                const f2v d23 = __builtin_amdgcn_cvt_scalef32_pk_f32_fp4(e_[i], 1.0f, 1); \
                const f2v d45 = __builtin_amdgcn_cvt_scalef32_pk_f32_fp4(e_[i], 1.0f, 2); \
                const f2v d67 = __builtin_amdgcn_cvt_scalef32_pk_f32_fp4(e_[i], 1.0f, 3); \
                a[0] = fmaf(w_[i], d01[0], a[0]);                                \
                a[1] = fmaf(w_[i], d01[1], a[1]);                                \
                a[2] = fmaf(w_[i], d23[0], a[2]);                                \
                a[3] = fmaf(w_[i], d23[1], a[3]);                                \
                a[4] = fmaf(w_[i], d45[0], a[4]);                                \
                a[5] = fmaf(w_[i], d45[1], a[5]);                                \
                a[6] = fmaf(w_[i], d67[0], a[6]);                                \
                a[7] = fmaf(w_[i], d67[1], a[7]);                                \
            }                                                                    \
        } while (0)
#else
    #define GATHER_DECODE(N, BASE)                                               \
        do {                                                                     \
            uint2 e_[N]; float w_[N];                                            \
            _Pragma("unroll")                                                    \
            for (int i = 0; i < N; ++i) {                                        \
                const float2 p = s_p[wave][(BASE) + i * 8 + grp];                \
                w_[i] = p.x;                                                     \
                e_[i] = *(const uint2*)&emb_tab[(size_t)__float_as_int(p.y) * 16 + c8 * 2]; \
            }                                                                    \
            _Pragma("unroll")                                                    \
            for (int i = 0; i < N; ++i) {                                        \
                const f2v d01 = __builtin_amdgcn_cvt_pk_f32_fp8((int)e_[i].x, false); \
                const f2v d23 = __builtin_amdgcn_cvt_pk_f32_fp8((int)e_[i].x, true);  \
                const f2v d45 = __builtin_amdgcn_cvt_pk_f32_fp8((int)e_[i].y, false); \
                const f2v d67 = __builtin_amdgcn_cvt_pk_f32_fp8((int)e_[i].y, true);  \
                a[0] = fmaf(w_[i], d01[0], a[0]);                                \
                a[1] = fmaf(w_[i], d01[1], a[1]);                                \
                a[2] = fmaf(w_[i], d23[0], a[2]);                                \
                a[3] = fmaf(w_[i], d23[1], a[3]);                                \
                a[4] = fmaf(w_[i], d45[0], a[4]);                                \
                a[5] = fmaf(w_[i], d45[1], a[5]);                                \
                a[6] = fmaf(w_[i], d67[0], a[6]);                                \
                a[7] = fmaf(w_[i], d67[1], a[7]);                                \
            }                                                                    \
        } while (0)
#endif

    GATHER_DECODE(16, 0);    // entries   0..127
    GATHER_DECODE(9, 128);   // entries 128..199

    #pragma unroll
    for (int off = 8; off <= 32; off <<= 1)
        #pragma unroll
        for (int j = 0; j < 8; ++j)
            a[j] += __shfl_xor(a[j], off, 64);

    if (grp == 0) {
        const float inv = 0.015625f / (wsum + 1e-8f);   // 1/64 descale folded in
        float4 o0 = make_float4(a[0]*inv, a[1]*inv, a[2]*inv, a[3]*inv);
        float4 o1 = make_float4(a[4]*inv, a[5]*inv, a[6]*inv, a[7]*inv);
        *(float4*)&hist_out[(size_t)b * DD + c8 * 8]     = o0;
        *(float4*)&hist_out[(size_t)b * DD + c8 * 8 + 4] = o1;
    }
}

//======================================================================
// X/H fragment slot: A-operand layout for mfma_f32_16x16x32_bf16
//======================================================================
#define PUT_FRAG(buf, NKS, r, d, val)                                   \
    do {                                                                \
        const int _mt = (r) >> 4, _ks = (d) >> 5;                       \
        const int _lp = (((d) >> 3) & 3) * 16 + ((r) & 15);             \
        (buf)[(((_mt) * (NKS) + _ks) * 64 + _lp) * 8 + ((d) & 7)] = f2bf(val); \
    } while (0)

//======================================================================
// Kernel 2: merged towers, M=32 rows/block, 32KB LDS, 1024 blocks total
// (one co-resident round at 4 blocks/CU). Wave = 1 ntile x 2 mtiles
// in L1 (halves weight L2 traffic to 2KB/row); L2 uses all 8 waves.
//======================================================================
__global__ __launch_bounds__(512)
void towers_kernel(
    const int* __restrict__ user_id, const int* __restrict__ top_genres,
    const int* __restrict__ item_id, const int* __restrict__ tmdb_genres,
    const float* __restrict__ hist_pool,
    const float* __restrict__ u_avg, const float* __restrict__ activity,
    const float* __restrict__ rel_year, const float* __restrict__ i_avg,
    const float* __restrict__ revenue,
    const float* __restrict__ emb_item, const float* __restrict__ emb_genre,
    const float* __restrict__ emb_user,
    const float* __restrict__ ut_cont_w, const float* __restrict__ ut_cont_b,
    const float* __restrict__ it_cont_w, const float* __restrict__ it_cont_b,
    const unsigned short* __restrict__ wblob,
    const float* __restrict__ ut_b1, const float* __restrict__ ut_g,
    const float* __restrict__ ut_be, const float* __restrict__ ut_b2,
    const float* __restrict__ it_b1, const float* __restrict__ it_g,
    const float* __restrict__ it_be, const float* __restrict__ it_b2,
    float* __restrict__ out, int B)
{
    const int tid = threadIdx.x, wave = tid >> 6, lane = tid & 63;
    const int nU = B / 32;
    const bool is_user = (int)blockIdx.x < nU;
    const int r0 = (is_user ? blockIdx.x : blockIdx.x - nU) * 32;

    __shared__ __align__(16) unsigned char  sXY[16 * 1024];  // sXf frags / sY f32 alias
    __shared__ __align__(16) unsigned short sHf[2 * 4 * 64 * 8]; // 8KB
    __shared__ __align__(16) float sO[32 * 64];              // 8KB

    unsigned short* sXf = (unsigned short*)sXY;
    float* sY = (float*)sXY;

    const f4v zero4 = {0.f, 0.f, 0.f, 0.f};
    const int mh2 = wave >> 2, nh2 = wave & 3;   // L2-layer wave roles

    if (is_user) {
        //---- features: wave handles rows wave*4 .. wave*4+3 ----
        #pragma unroll
        for (int i = 0; i < 4; ++i) {
            const int r = wave * 4 + i, b = r0 + r;
            const float ue = emb_user[(size_t)user_id[b] * DD + lane];
            const float hp = hist_pool[(size_t)b * DD + lane];
            const int* grow = top_genres + (size_t)b * GG;
            float gacc = 0.f, gw = 0.f;
            #pragma unroll
            for (int g = 0; g < GG; ++g) {
                const int idx = grow[g];
                const float m = (idx > 0) ? 1.f : 0.f;
                gacc = fmaf(m, emb_genre[idx * DD + lane], gacc);
                gw += m;
            }
            const float ug = gacc / (gw + 1e-8f);
            float uc = fmaf(u_avg[b], ut_cont_w[lane * 2 + 0],
                       fmaf(activity[b], ut_cont_w[lane * 2 + 1], ut_cont_b[lane]));
            uc = fmaxf(uc, 0.f);
            PUT_FRAG(sXf, 8, r, lane, ue);
            PUT_FRAG(sXf, 8, r, 64 + lane, hp);
            PUT_FRAG(sXf, 8, r, 128 + lane, ug);
            PUT_FRAG(sXf, 8, r, 192 + lane, uc);
        }
        __syncthreads();

        //---- L1 MFMA: M=32, N=128, K=256; wave = ntile, both mtiles ----
        f4v acc[2];
        acc[0] = zero4; acc[1] = zero4;
        #pragma unroll
        for (int ks = 0; ks < 8; ++ks) {
            const s8v bv = *(const s8v*)&wblob[((ks * 8 + wave) * 64 + lane) * 8];
            #pragma unroll
            for (int ml = 0; ml < 2; ++ml) {
                const s8v av = *(const s8v*)&sXf[(((ml * 8 + ks)) * 64 + lane) * 8];
                acc[ml] = __builtin_amdgcn_mfma_f32_16x16x32_bf16(av, bv, acc[ml], 0, 0, 0);
            }
        }
        __syncthreads();   // done reading sXf

        //---- y = acc + b1 -> sY [32][128] ----
        {
            const int n = wave * 16 + (lane & 15);
            const float bb = ut_b1[n];
            #pragma unroll
            for (int ml = 0; ml < 2; ++ml)
                #pragma unroll
                for (int rg = 0; rg < 4; ++rg) {
                    const int m = ml * 16 + (lane >> 4) * 4 + rg;
                    sY[m * 128 + n] = acc[ml][rg] + bb;
                }
        }
        __syncthreads();

        //---- LN + ReLU (held in regs, then frag write after barrier) ----
        float h0[4], h1[4];
        {
            const float g0 = ut_g[lane], g1 = ut_g[lane + 64];
            const float e0 = ut_be[lane], e1 = ut_be[lane + 64];
            #pragma unroll
            for (int i = 0; i < 4; ++i) {
                const int r = wave * 4 + i;
                const float a = sY[r * 128 + lane];
                const float c = sY[r * 128 + 64 + lane];
                const float mean = wave_reduce_sum(a + c) * (1.f / 128.f);
                const float da = a - mean, dc = c - mean;
                const float var = wave_reduce_sum(da * da + dc * dc) * (1.f / 128.f);
                const float rstd = rsqrtf(var + 1e-5f);
                h0[i] = fmaxf(fmaf(da * rstd, g0, e0), 0.f);
                h1[i] = fmaxf(fmaf(dc * rstd, g1, e1), 0.f);
            }
        }
        #pragma unroll
        for (int i = 0; i < 4; ++i) {
            const int r = wave * 4 + i;
            PUT_FRAG(sHf, 4, r, lane, h0[i]);
            PUT_FRAG(sHf, 4, r, 64 + lane, h1[i]);
        }
        __syncthreads();

        //---- L2 MFMA: M=32, N=64, K=128; wave = (mtile, ntile) ----
        {
            f4v acc2 = zero4;
            #pragma unroll
            for (int ks = 0; ks < 4; ++ks) {
                const s8v av = *(const s8v*)&sHf[((mh2 * 4 + ks) * 64 + lane) * 8];
                const s8v bv = *(const s8v*)&wblob[(4096 + (ks * 4 + nh2) * 64 + lane) * 8];
                acc2 = __builtin_amdgcn_mfma_f32_16x16x32_bf16(av, bv, acc2, 0, 0, 0);
            }
            const int n = nh2 * 16 + (lane & 15);
            const float bb = ut_b2[n];
            #pragma unroll
            for (int rg = 0; rg < 4; ++rg) {
                const int m = mh2 * 16 + (lane >> 4) * 4 + rg;
                sO[m * 64 + n] = acc2[rg] + bb;
            }
        }
        __syncthreads();

        //---- l2norm + store ----
        #pragma unroll
        for (int i = 0; i < 4; ++i) {
            const int r = wave * 4 + i;
            const float o = sO[r * 64 + lane];
            const float nrm = sqrtf(wave_reduce_sum(o * o));
            out[(size_t)(r0 + r) * DD + lane] = o / fmaxf(nrm, 1e-12f);
        }
    } else {
        //================= item tower, M=32 =================
        #pragma unroll
        for (int i = 0; i < 4; ++i) {
            const int r = wave * 4 + i, b = r0 + r;
            const float ie = emb_item[(size_t)item_id[b] * DD + lane];
            const int* grow = tmdb_genres + (size_t)b * GG;
            float gacc = 0.f, gw = 0.f;
            #pragma unroll
            for (int g = 0; g < GG; ++g) {
                const int idx = grow[g];
                const float m = (idx > 0) ? 1.f : 0.f;
                gacc = fmaf(m, emb_genre[idx * DD + lane], gacc);
                gw += m;
            }
            const float ig = gacc / (gw + 1e-8f);
            float ic = fmaf(rel_year[b], it_cont_w[lane * 3 + 0],
                       fmaf(i_avg[b],   it_cont_w[lane * 3 + 1],
                       fmaf(revenue[b], it_cont_w[lane * 3 + 2], it_cont_b[lane])));
            ic = fmaxf(ic, 0.f);
            PUT_FRAG(sXf, 6, r, lane, ie);
            PUT_FRAG(sXf, 6, r, 64 + lane, ig);
            PUT_FRAG(sXf, 6, r, 128 + lane, ic);
        }
        __syncthreads();

        //---- L1 MFMA: M=32, N=128, K=192 ----
        f4v acc[2];
        acc[0] = zero4; acc[1] = zero4;
        #pragma unroll
        for (int ks = 0; ks < 6; ++ks) {
            const s8v bv = *(const s8v*)&wblob[(5120 + (ks * 8 + wave) * 64 + lane) * 8];
            #pragma unroll
            for (int ml = 0; ml < 2; ++ml) {
                const s8v av = *(const s8v*)&sXf[(((ml * 6 + ks)) * 64 + lane) * 8];
                acc[ml] = __builtin_amdgcn_mfma_f32_16x16x32_bf16(av, bv, acc[ml], 0, 0, 0);
            }
        }
        __syncthreads();

        {
            const int n = wave * 16 + (lane & 15);
            const float bb = it_b1[n];
            #pragma unroll
            for (int ml = 0; ml < 2; ++ml)
                #pragma unroll
                for (int rg = 0; rg < 4; ++rg) {
                    const int m = ml * 16 + (lane >> 4) * 4 + rg;
                    sY[m * 128 + n] = acc[ml][rg] + bb;
                }
        }
        __syncthreads();

        float h0[4], h1[4];
        {
            const float g0 = it_g[lane], g1 = it_g[lane + 64];
            const float e0 = it_be[lane], e1 = it_be[lane + 64];
            #pragma unroll
            for (int i = 0; i < 4; ++i) {
                const int r = wave * 4 + i;
                const float a = sY[r * 128 + lane];
                const float c = sY[r * 128 + 64 + lane];
                const float mean = wave_reduce_sum(a + c) * (1.f / 128.f);
                const float da = a - mean, dc = c - mean;
                const float var = wave_reduce_sum(da * da + dc * dc) * (1.f / 128.f);
                const float rstd = rsqrtf(var + 1e-5f);
                h0[i] = fmaxf(fmaf(da * rstd, g0, e0), 0.f);
                h1[i] = fmaxf(fmaf(dc * rstd, g1, e1), 0.f);
            }
        }
        #pragma unroll
        for (int i = 0; i < 4; ++i) {
            const int r = wave * 4 + i;
            PUT_FRAG(sHf, 4, r, lane, h0[i]);
            PUT_FRAG(sHf, 4, r, 64 + lane, h1[i]);
        }
        __syncthreads();

        {
            f4v acc2 = zero4;
            #pragma unroll
            for (int ks = 0; ks < 4; ++ks) {
                const s8v av = *(const s8v*)&sHf[((mh2 * 4 + ks) * 64 + lane) * 8];
                const s8v bv = *(const s8v*)&wblob[(8192 + (ks * 4 + nh2) * 64 + lane) * 8];
                acc2 = __builtin_amdgcn_mfma_f32_16x16x32_bf16(av, bv, acc2, 0, 0, 0);
            }
            const int n = nh2 * 16 + (lane & 15);
            const float bb = it_b2[n];
            #pragma unroll
            for (int rg = 0; rg < 4; ++rg) {
                const int m = mh2 * 16 + (lane >> 4) * 4 + rg;
                sO[m * 64 + n] = acc2[rg] + bb;
            }
        }
        __syncthreads();

        #pragma unroll
        for (int i = 0; i < 4; ++i) {
            const int r = wave * 4 + i;
            const float o = sO[r * 64 + lane];
            const float nrm = sqrtf(wave_reduce_sum(o * o));
            out[(size_t)B * DD + (size_t)(r0 + r) * DD + lane] = o / fmaxf(nrm, 1e-12f);
        }
    }
}

extern "C" void kernel_launch(void* const* d_in, const int* in_sizes, int n_in,
                              void* d_out, int out_size, void* d_ws, size_t ws_size,
                              hipStream_t stream) {
    const int*   user_id     = (const int*)  d_in[0];
    const int*   history     = (const int*)  d_in[1];
    const int*   top_genres  = (const int*)  d_in[2];
    const int*   item_id     = (const int*)  d_in[3];
    const int*   tmdb_genres = (const int*)  d_in[4];
    const float* ts_diff     = (const float*)d_in[5];
    const float* u_avg       = (const float*)d_in[6];
    const float* activity    = (const float*)d_in[7];
    const float* rel_year    = (const float*)d_in[8];
    const float* i_avg       = (const float*)d_in[9];
    const float* revenue     = (const float*)d_in[10];
    const float* emb_item    = (const float*)d_in[11];
    const float* emb_genre   = (const float*)d_in[12];
    const float* emb_user    = (const float*)d_in[13];
    const float* ut_cont_w   = (const float*)d_in[14];
    const float* ut_cont_b   = (const float*)d_in[15];
    const float* ut_w1       = (const float*)d_in[16];
    const float* ut_b1       = (const float*)d_in[17];
    const float* ut_g        = (const float*)d_in[18];
    const float* ut_be       = (const float*)d_in[19];
    const float* ut_w2       = (const float*)d_in[20];
    const float* ut_b2       = (const float*)d_in[21];
    const float* it_cont_w   = (const float*)d_in[22];
    const float* it_cont_b   = (const float*)d_in[23];
    const float* it_w1       = (const float*)d_in[24];
    const float* it_b1       = (const float*)d_in[25];
    const float* it_g        = (const float*)d_in[26];
    const float* it_be       = (const float*)d_in[27];
    const float* it_w2       = (const float*)d_in[28];
    const float* it_b2       = (const float*)d_in[29];

    const int B = in_sizes[0];                 // 16384
    const int n_item = in_sizes[11];           // V_ITEM * 64
    const int V = n_item / DD;                 // 100001

    // workspace layout (reserve fp8-size table regardless of path)
    unsigned int* emb_tab = (unsigned int*)d_ws;                      // <= 6.4MB
    size_t off = (size_t)(n_item / 4) * sizeof(unsigned int);
    off = (off + 255) & ~(size_t)255;
    unsigned short* wblob = (unsigned short*)((char*)d_ws + off);     // 144KB
    off += (size_t)9216 * 8 * sizeof(unsigned short);
    off = (off + 255) & ~(size_t)255;
    float* hist_pool = (float*)((char*)d_ws + off);                   // 4MB

    hipLaunchKernelGGL(prep_kernel, dim3(PREP_BLOCKS + 36), dim3(256), 0, stream,
        emb_item, ut_w1, ut_w2, it_w1, it_w2, emb_tab, wblob, V);

    hipLaunchKernelGGL(hist_pool_kernel, dim3(B / 4), dim3(256), 0, stream,
        history, ts_diff, emb_tab, hist_pool, B);

    hipLaunchKernelGGL(towers_kernel, dim3(2 * (B / 32)), dim3(512), 0, stream,
        user_id, top_genres, item_id, tmdb_genres, hist_pool,
        u_avg, activity, rel_year, i_avg, revenue,
        emb_item, emb_genre, emb_user,
        ut_cont_w, ut_cont_b, it_cont_w, it_cont_b,
        wblob, ut_b1, ut_g, ut_be, ut_b2, it_b1, it_g, it_be, it_b2,
        (float*)d_out, B);
}